// Round 8
// baseline (402.462 us; speedup 1.0000x reference)
//
#include <hip/hip_runtime.h>

// QKNorm MHA: B=2, L=2048, D=2048, H=16, hd=128.
// Round 8: GEMMs rewritten as 256x256-tile, BK=32, 8-wave kernel with a
// 4-slot LDS ring (128 KiB), counted s_waitcnt vmcnt(8) (never 0 in main
// loop), raw s_barrier, XOR-swizzled LDS (2-way free), setprio, XCD-chunked
// N-panels. Attention (attn4) unchanged from round 7.

#define DM   2048
#define HD   128
#define NH   16
#define LSEQ 2048
#define NB   2
#define MTOK 4096  // NB*LSEQ
#define QKVS 6144  // fused row stride

typedef __bf16 bf16x8 __attribute__((ext_vector_type(8)));
typedef float  f32x4  __attribute__((ext_vector_type(4)));

__device__ __forceinline__ unsigned short f2bf(float f) {
  unsigned u = __builtin_bit_cast(unsigned, f);
  u += 0x7fffu + ((u >> 16) & 1u);
  return (unsigned short)(u >> 16);
}
__device__ __forceinline__ unsigned packbf(float lo, float hi) {
  return (unsigned)f2bf(lo) | ((unsigned)f2bf(hi) << 16);
}
__device__ __forceinline__ float bf2f(unsigned short h) {
  unsigned u = ((unsigned)h) << 16;
  return __builtin_bit_cast(float, u);
}
__device__ __forceinline__ void gload16(const unsigned short* gc, unsigned short* l) {
  unsigned short* g = const_cast<unsigned short*>(gc);
  __builtin_amdgcn_global_load_lds((__attribute__((address_space(1))) void*)g,
                                   (__attribute__((address_space(3))) void*)l, 16, 0, 0);
}
__device__ __forceinline__ bf16x8 ld_frag(const void* p) {
  return __builtin_bit_cast(bf16x8, *(const uint4*)p);
}

// ---------------- f32 -> bf16 convert (8 elems/thread) ----------------
__global__ void cvt_bf16_k(const float* __restrict__ s, unsigned short* __restrict__ d, int n8) {
  int i = blockIdx.x * blockDim.x + threadIdx.x;
  if (i >= n8) return;
  const float4* s4 = (const float4*)s;
  float4 a = s4[2 * i], b = s4[2 * i + 1];
  uint4 o;
  o.x = packbf(a.x, a.y);
  o.y = packbf(a.z, a.w);
  o.z = packbf(b.x, b.y);
  o.w = packbf(b.z, b.w);
  ((uint4*)d)[i] = o;
}

// ---------------- bias concat [bq|bk|bv] -> f32[6144] ----------------
__global__ void bcat_k(const float* __restrict__ bq, const float* __restrict__ bk,
                       const float* __restrict__ bv, float* __restrict__ o) {
  int i = blockIdx.x * blockDim.x + threadIdx.x;
  if (i >= QKVS) return;
  float v = (i < 2048) ? bq[i] : (i < 4096) ? bk[i - 2048] : bv[i - 4096];
  o[i] = v;
}

// ============ GEMM 256x256, BK=32, 4-slot ring, counted vmcnt ============
// C[M,N] = A[M,K]*B[N,K]^T + bias. 512 threads = 8 waves (2M x 4N),
// per-wave 128x64 output (acc[8][4]). LDS 128 KiB.
// Swizzle: LDS image chunk (row, ch) holds global chunk (row, ch^((row>>1)&3));
// both the global source (stage) and the ds_read apply the same XOR.
template <int OUT_BF16>
__global__ __launch_bounds__(512) void gemm256_bt(
    const unsigned short* __restrict__ A, const unsigned short* __restrict__ Bm,
    const float* __restrict__ bias, void* __restrict__ Cv, int M, int N, int K) {
  __shared__ unsigned short Ab[4][256 * 32];
  __shared__ unsigned short Bb[4][256 * 32];
  const int tid = threadIdx.x, wave = tid >> 6, lane = tid & 63;
  const int l15 = lane & 15, l4 = lane >> 4;
  const int wr = wave >> 2, wc = wave & 3;

  // XCD-chunked block mapping: each XCD owns np/8 N-panels (L2-resident W).
  const int np = N >> 8;
  int n_id, m_id;
  if ((np & 7) == 0) {
    int cpx = np >> 3;
    int xcd = blockIdx.x & 7, r = blockIdx.x >> 3;
    n_id = xcd * cpx + r % cpx;
    m_id = r / cpx;
  } else {
    n_id = blockIdx.x % np;
    m_id = blockIdx.x / np;
  }
  const size_t ra0 = (size_t)m_id * 256, rb0 = (size_t)n_id * 256;
  const int NT = K >> 5;  // BK=32 tiles (>=4 required; K=2048 -> 64)

  // staging coords (2 rounds per matrix, 4 gloads/thread/tile)
  int srow[2], sch[2];
#pragma unroll
  for (int j = 0; j < 2; j++) {
    int c = j * 512 + tid;
    srow[j] = c >> 2;
    sch[j] = (c & 3) ^ ((srow[j] >> 1) & 3);
  }

#define STAGE(kt, s)                                                                   \
  {                                                                                    \
    const int k0_ = (kt) << 5;                                                         \
    _Pragma("unroll") for (int j = 0; j < 2; j++) {                                    \
      gload16(A + (ra0 + srow[j]) * (size_t)K + k0_ + sch[j] * 8,                      \
              &Ab[s][(j * 512 + wave * 64) * 8]);                                      \
      gload16(Bm + (rb0 + srow[j]) * (size_t)K + k0_ + sch[j] * 8,                     \
              &Bb[s][(j * 512 + wave * 64) * 8]);                                      \
    }                                                                                  \
  }

  f32x4 acc[8][4] = {};

#define COMPUTE(s)                                                                     \
  {                                                                                    \
    char* Ap = (char*)&Ab[s][0];                                                       \
    char* Bp = (char*)&Bb[s][0];                                                       \
    bf16x8 bf[4], af[8];                                                               \
    _Pragma("unroll") for (int n = 0; n < 4; n++) {                                    \
      int row = wc * 64 + n * 16 + l15;                                                \
      bf[n] = ld_frag(Bp + row * 64 + ((l4 ^ ((row >> 1) & 3)) << 4));                 \
    }                                                                                  \
    _Pragma("unroll") for (int m = 0; m < 8; m++) {                                    \
      int row = wr * 128 + m * 16 + l15;                                               \
      af[m] = ld_frag(Ap + row * 64 + ((l4 ^ ((row >> 1) & 3)) << 4));                 \
    }                                                                                  \
    __builtin_amdgcn_s_setprio(1);                                                     \
    _Pragma("unroll") for (int m = 0; m < 8; m++)                                      \
        _Pragma("unroll") for (int n = 0; n < 4; n++)                                  \
            acc[m][n] =                                                                \
                __builtin_amdgcn_mfma_f32_16x16x32_bf16(af[m], bf[n], acc[m][n], 0, 0, 0); \
    __builtin_amdgcn_s_setprio(0);                                                     \
  }

  // prologue: stage tiles 0,1,2 (12 loads); wait oldest 4 (tile 0)
  STAGE(0, 0)
  STAGE(1, 1)
  STAGE(2, 2)
  asm volatile("s_waitcnt vmcnt(8)" ::: "memory");
  __builtin_amdgcn_s_barrier();

  for (int t = 0; t < NT - 3; ++t) {
    STAGE(t + 3, (t + 3) & 3)
    COMPUTE(t & 3)
    // 12 outstanding (t+1,t+2,t+3); drain to 8 => tile t+1 landed (FIFO)
    asm volatile("s_waitcnt vmcnt(8)" ::: "memory");
    __builtin_amdgcn_s_barrier();
  }
  COMPUTE((NT - 3) & 3)
  asm volatile("s_waitcnt vmcnt(4)" ::: "memory");
  __builtin_amdgcn_s_barrier();
  COMPUTE((NT - 2) & 3)
  asm volatile("s_waitcnt vmcnt(0)" ::: "memory");
  __builtin_amdgcn_s_barrier();
  COMPUTE((NT - 1) & 3)

  // epilogue
  const int row0 = m_id * 256 + wr * 128;
  const int col0 = n_id * 256 + wc * 64;
#pragma unroll
  for (int n = 0; n < 4; n++) {
    int col = col0 + n * 16 + l15;
    float bv = bias[col];
#pragma unroll
    for (int m = 0; m < 8; m++) {
      int rowb = row0 + m * 16 + l4 * 4;
#pragma unroll
      for (int r = 0; r < 4; r++) {
        float v = acc[m][n][r] + bv;
        if (OUT_BF16)
          ((unsigned short*)Cv)[(size_t)(rowb + r) * N + col] = f2bf(v);
        else
          ((float*)Cv)[(size_t)(rowb + r) * N + col] = v;
      }
    }
  }
#undef STAGE
#undef COMPUTE
}

// ------- in-place L2 normalize K rows (strided layout inside qkv) -------
__global__ void qknorm_s_k(unsigned short* __restrict__ qkv) {
  int row = blockIdx.x * 4 + (threadIdx.x >> 6);  // token*16+head
  int lane = threadIdx.x & 63;
  int t = row >> 4, h = row & 15;
  unsigned* p = (unsigned*)(qkv + (size_t)t * QKVS + 2048 + h * HD);
  unsigned w = p[lane];
  float a = bf2f((unsigned short)(w & 0xffff));
  float b = bf2f((unsigned short)(w >> 16));
  float ss = a * a + b * b;
#pragma unroll
  for (int m = 1; m < 64; m <<= 1) ss += __shfl_xor(ss, m);
  float inv = 1.0f / (sqrtf(ss) + 1e-6f);
  p[lane] = packbf(a * inv, b * inv);
}

// ---- V transpose: Vt[bh][d][l] = qkv[b,l][4096 + h*HD + d] ----
__global__ void vtrans_k(const unsigned short* __restrict__ QKV, unsigned short* __restrict__ Vt) {
  __shared__ unsigned short t[128 * 136];
  const int bh = blockIdx.y, b = bh >> 4, h = bh & 15;
  const int l0 = blockIdx.x * 128;
  const int tid = threadIdx.x;
#pragma unroll
  for (int i = 0; i < 8; i++) {
    int s = i * 256 + tid;
    int r = s >> 4, c8 = (s & 15) * 8;
    uint4 v = *(const uint4*)(QKV + ((size_t)(b * LSEQ + l0 + r)) * QKVS + 4096 + h * HD + c8);
    *(uint4*)&t[r * 136 + c8] = v;
  }
  __syncthreads();
#pragma unroll
  for (int i = 0; i < 8; i++) {
    int s = i * 256 + tid;
    int dd = s >> 4, l8 = (s & 15) * 8;
    unsigned short tmp[8];
#pragma unroll
    for (int j = 0; j < 8; j++) tmp[j] = t[(l8 + j) * 136 + dd];
    *(uint4*)(Vt + ((size_t)bh * HD + dd) * LSEQ + l0 + l8) = *(const uint4*)tmp;
  }
}

// ---------------- attention v4 (unchanged from round 7) ----------------
__global__ __launch_bounds__(256) void attn4_k(
    const unsigned short* __restrict__ QKV, const unsigned short* __restrict__ Vt,
    unsigned short* __restrict__ Na, unsigned short* __restrict__ Nb,
    float* __restrict__ Dw) {
  __shared__ __align__(16) unsigned short Ks[2][32 * 128];  // pitch 256B, XOR (row&7)<<4
  __shared__ __align__(16) unsigned short Vs[2][128 * 40];  // pitch 80B, no XOR

  const int id = blockIdx.x;
  const int xcd = id & 7, sl = id >> 3;
  const int bh = xcd * 4 + (sl >> 5);
  const int kvh = (sl >> 4) & 1, qb = sl & 15;
  const int b = bh >> 4, h = bh & 15;
  const int q0 = qb * 128;
  const int kvbase = kvh * (LSEQ / 2);
  const int tid = threadIdx.x, wave = tid >> 6, lane = tid & 63;
  const int l15 = lane & 15, l4 = lane >> 4;
  const float scale = 0.08838834764831845f;  // 1/sqrt(128)

  bf16x8 qf[2][4];
#pragma unroll
  for (int rg = 0; rg < 2; rg++) {
    const unsigned short* qp =
        QKV + ((size_t)(b * LSEQ + q0 + wave * 32 + rg * 16 + l15)) * QKVS + h * HD + l4 * 8;
    uint4 qv[4];
    float qs[4][8];
    float ss = 0.f;
#pragma unroll
    for (int kk = 0; kk < 4; kk++) qv[kk] = *(const uint4*)(qp + kk * 32);
#pragma unroll
    for (int kk = 0; kk < 4; kk++) {
      const unsigned* w = (const unsigned*)&qv[kk];
#pragma unroll
      for (int m = 0; m < 4; m++) {
        float a = bf2f((unsigned short)(w[m] & 0xffff));
        float c = bf2f((unsigned short)(w[m] >> 16));
        qs[kk][2 * m] = a; qs[kk][2 * m + 1] = c;
        ss += a * a + c * c;
      }
    }
    ss += __shfl_xor(ss, 16);
    ss += __shfl_xor(ss, 32);
    float inv = 1.0f / (sqrtf(ss) + 1e-6f);
    uint4 qo;
    unsigned* wo = (unsigned*)&qo;
#pragma unroll
    for (int kk = 0; kk < 4; kk++) {
#pragma unroll
      for (int m = 0; m < 4; m++)
        wo[m] = packbf(qs[kk][2 * m] * inv, qs[kk][2 * m + 1] * inv);
      qf[rg][kk] = __builtin_bit_cast(bf16x8, qo);
    }
  }

  f32x4 oacc[2][8] = {};
  float den[2] = {0.f, 0.f};
  uint4 pk[2], pv[2];

  const unsigned short* Kb = QKV + ((size_t)(b * LSEQ)) * QKVS + 2048 + h * HD;
  const unsigned short* Vb = Vt + ((size_t)bh * HD) * LSEQ;
  const int kr0 = tid >> 4, kc = tid & 15;
  const int vr0 = tid >> 2, vc = tid & 3;
  const int srcA = ((l4 * 2) & 3) * 16 + l15;
  const int srcB = ((l4 * 2 + 1) & 3) * 16 + l15;
  const bool hiSel = (l4 >= 2);

#pragma unroll
  for (int i = 0; i < 2; i++) {
    pk[i] = *(const uint4*)(Kb + (size_t)(kvbase + kr0 + i * 16) * QKVS + kc * 8);
    pv[i] = *(const uint4*)(Vb + (size_t)(vr0 + i * 64) * LSEQ + kvbase + vc * 8);
  }
#pragma unroll
  for (int i = 0; i < 2; i++) {
    int kr = kr0 + i * 16;
    *(uint4*)((char*)&Ks[0][0] + kr * 256 + ((kc ^ (kr & 7)) << 4)) = pk[i];
    int vr = vr0 + i * 64;
    *(uint4*)((char*)&Vs[0][0] + vr * 80 + vc * 16) = pv[i];
  }

  for (int t = 0; t < 32; t++) {
    const int cur = t & 1;
    __syncthreads();
    if (t + 1 < 32) {
      const int kvn = kvbase + (t + 1) * 32;
#pragma unroll
      for (int i = 0; i < 2; i++) {
        pk[i] = *(const uint4*)(Kb + (size_t)(kvn + kr0 + i * 16) * QKVS + kc * 8);
        pv[i] = *(const uint4*)(Vb + (size_t)(vr0 + i * 64) * LSEQ + kvn + vc * 8);
      }
    }

    f32x4 sacc[2][2] = {};
    char* ksb = (char*)&Ks[cur][0];
    __builtin_amdgcn_s_setprio(1);
#pragma unroll
    for (int ni = 0; ni < 2; ni++) {
#pragma unroll
      for (int kk = 0; kk < 4; kk++) {
        bf16x8 kf = ld_frag(ksb + (ni * 16 + l15) * 256 + (((kk * 4 + l4) ^ (l15 & 7)) << 4));
        sacc[0][ni] = __builtin_amdgcn_mfma_f32_16x16x32_bf16(kf, qf[0][kk], sacc[0][ni], 0, 0, 0);
        sacc[1][ni] = __builtin_amdgcn_mfma_f32_16x16x32_bf16(kf, qf[1][kk], sacc[1][ni], 0, 0, 0);
      }
    }
    __builtin_amdgcn_s_setprio(0);

    bf16x8 pa[2];
#pragma unroll
    for (int rg = 0; rg < 2; rg++) {
      float pe[4], po[4];
#pragma unroll
      for (int r = 0; r < 4; r++) {
        pe[r] = __expf(sacc[rg][0][r] * scale);
        po[r] = __expf(sacc[rg][1][r] * scale);
      }
      den[rg] += (pe[0] + pe[1]) + (pe[2] + pe[3]) + (po[0] + po[1]) + (po[2] + po[3]);
      unsigned c0e = packbf(pe[0], pe[1]), c1e = packbf(pe[2], pe[3]);
      unsigned c0o = packbf(po[0], po[1]), c1o = packbf(po[2], po[3]);
      unsigned a0 = __shfl(c0e, srcA), a1 = __shfl(c0o, srcA);
      unsigned b0 = __shfl(c1e, srcA), b1 = __shfl(c1o, srcA);
      unsigned c0 = __shfl(c0e, srcB), c1 = __shfl(c0o, srcB);
      unsigned d0_ = __shfl(c1e, srcB), d1 = __shfl(c1o, srcB);
      uint4 paw;
      paw.x = hiSel ? a1 : a0;
      paw.y = hiSel ? b1 : b0;
      paw.z = hiSel ? c1 : c0;
      paw.w = hiSel ? d1 : d0_;
      pa[rg] = __builtin_bit_cast(bf16x8, paw);
    }

    char* vsb = (char*)&Vs[cur][0];
    __builtin_amdgcn_s_setprio(1);
#pragma unroll
    for (int d0 = 0; d0 < 8; d0++) {
      bf16x8 vf = ld_frag(vsb + (d0 * 16 + l15) * 80 + l4 * 16);
      oacc[0][d0] = __builtin_amdgcn_mfma_f32_16x16x32_bf16(pa[0], vf, oacc[0][d0], 0, 0, 0);
      oacc[1][d0] = __builtin_amdgcn_mfma_f32_16x16x32_bf16(pa[1], vf, oacc[1][d0], 0, 0, 0);
    }
    __builtin_amdgcn_s_setprio(0);

    if (t + 1 < 32) {
      char* ksn = (char*)&Ks[cur ^ 1][0];
      char* vsn = (char*)&Vs[cur ^ 1][0];
#pragma unroll
      for (int i = 0; i < 2; i++) {
        int kr = kr0 + i * 16;
        *(uint4*)(ksn + kr * 256 + ((kc ^ (kr & 7)) << 4)) = pk[i];
        int vr = vr0 + i * 64;
        *(uint4*)(vsn + vr * 80 + vc * 16) = pv[i];
      }
    }
  }

  unsigned short* Np = kvh ? Nb : Na;
#pragma unroll
  for (int rg = 0; rg < 2; rg++) {
    float sd = den[rg];
    sd += __shfl_xor(sd, 16);
    sd += __shfl_xor(sd, 32);
    if (l4 == 0) {
      int token = b * LSEQ + q0 + wave * 32 + rg * 16 + l15;
      Dw[((size_t)kvh * MTOK + token) * NH + h] = sd;
    }
  }
#pragma unroll
  for (int rg = 0; rg < 2; rg++)
#pragma unroll
    for (int d0 = 0; d0 < 8; d0++)
#pragma unroll
      for (int r = 0; r < 4; r++) {
        int token = b * LSEQ + q0 + wave * 32 + rg * 16 + l4 * 4 + r;
        Np[(size_t)token * DM + h * HD + d0 * 16 + l15] = f2bf(oacc[rg][d0][r]);
      }
}

// ---------------- combine: ao = (n0+n1)/(d0+d1) ----------------
__global__ void comb_k(const unsigned short* __restrict__ Na,
                       const unsigned short* __restrict__ Nb,
                       const float* __restrict__ Dw, unsigned short* __restrict__ Ao) {
  int i = blockIdx.x * 256 + threadIdx.x;
  int token = i >> 8, c8 = i & 255;
  int h = c8 >> 4;
  float d = Dw[(size_t)token * NH + h] + Dw[(size_t)(MTOK + token) * NH + h];
  float inv = 1.0f / d;
  uint4 w0 = ((const uint4*)Na)[i];
  uint4 w1 = ((const uint4*)Nb)[i];
  const unsigned* a = (const unsigned*)&w0;
  const unsigned* bq = (const unsigned*)&w1;
  uint4 o;
  unsigned* ow = (unsigned*)&o;
#pragma unroll
  for (int m = 0; m < 4; m++) {
    float lo = (bf2f((unsigned short)(a[m] & 0xffff)) + bf2f((unsigned short)(bq[m] & 0xffff))) * inv;
    float hi = (bf2f((unsigned short)(a[m] >> 16)) + bf2f((unsigned short)(bq[m] >> 16))) * inv;
    ow[m] = packbf(lo, hi);
  }
  ((uint4*)Ao)[i] = o;
}

extern "C" void kernel_launch(void* const* d_in, const int* in_sizes, int n_in,
                              void* d_out, int out_size, void* d_ws, size_t ws_size,
                              hipStream_t stream) {
  const float* x  = (const float*)d_in[0];
  const float* Wq = (const float*)d_in[1];
  const float* bq = (const float*)d_in[2];
  const float* Wk = (const float*)d_in[3];
  const float* bk = (const float*)d_in[4];
  const float* Wv = (const float*)d_in[5];
  const float* bv = (const float*)d_in[6];
  const float* Wo = (const float*)d_in[7];
  const float* bo = (const float*)d_in[8];

  char* ws = (char*)d_ws;
  unsigned short* xb   = (unsigned short*)(ws + 0);          // [0,16M): x bf16 -> num partial A
  unsigned short* wqkv = (unsigned short*)(ws + 16777216);   // [16M,40M): Wq|Wk|Wv bf16
  unsigned short* wob  = (unsigned short*)(ws + 41943040);   // [40M,48M): Wo bf16
  float*          bqkv = (float*)(ws + 50331648);            // [48M,+24K)
  unsigned short* qkv  = (unsigned short*)(ws + 50364416);   // [48.03M,+48M)
  unsigned short* vt   = wqkv;                                // [16M,32M) after QKV gemm
  float*          dwp  = (float*)(ws + 33554432);            // [32M,32.5M) after QKV gemm
  unsigned short* na   = xb;                                  // [0,16M) after QKV gemm
  unsigned short* nb   = (unsigned short*)d_out;              // first 16M of d_out as scratch
  unsigned short* ao   = qkv;                                 // [48.03M,+16M) after attn

  // casts
  cvt_bf16_k<<<4096, 256, 0, stream>>>(x, xb, MTOK * DM / 8);
  cvt_bf16_k<<<2048, 256, 0, stream>>>(Wq, wqkv, DM * DM / 8);
  cvt_bf16_k<<<2048, 256, 0, stream>>>(Wk, wqkv + 2048 * 2048, DM * DM / 8);
  cvt_bf16_k<<<2048, 256, 0, stream>>>(Wv, wqkv + 4096 * 2048, DM * DM / 8);
  cvt_bf16_k<<<2048, 256, 0, stream>>>(Wo, wob, DM * DM / 8);
  bcat_k<<<24, 256, 0, stream>>>(bq, bk, bv, bqkv);

  // fused QKV projection: [4096,6144] = xb * wqkv^T + bqkv  (256^2 ring kernel)
  gemm256_bt<1><<<(MTOK / 256) * (QKVS / 256), 512, 0, stream>>>(xb, wqkv, bqkv, qkv,
                                                                 MTOK, QKVS, DM);

  // K-norm in place (Q-norm fused in attn)
  qknorm_s_k<<<MTOK * NH / 4, 256, 0, stream>>>(qkv);

  // V transpose per head (into dead weight buffer)
  vtrans_k<<<dim3(LSEQ / 128, NB * NH), 256, 0, stream>>>(qkv, vt);

  // attention v4 with KV-split x2
  attn4_k<<<1024, 256, 0, stream>>>(qkv, vt, na, nb, dwp);

  // combine partials -> ao (bf16)
  comb_k<<<4096, 256, 0, stream>>>(na, nb, dwp, ao);

  // output projection (f32 out, 256^2 ring kernel)
  gemm256_bt<0><<<(MTOK / 256) * (DM / 256), 512, 0, stream>>>(ao, wob, bo, (float*)d_out,
                                                               MTOK, DM, DM);
}

// Round 9
// 352.759 us; speedup vs baseline: 1.1409x; 1.1409x over previous
//
#include <hip/hip_runtime.h>

// QKNorm MHA: B=2, L=2048, D=2048, H=16, hd=128.
// Round 9: 256^2 GEMM rebuilt as true 8-phase schedule (BK=64, 4 phases/K-tile):
// per phase {ds_read subtile; stage 1 half-tile; s_barrier; setprio; 16 MFMA;
// setprio; s_barrier}. A double-buffered, B TRI-buffered (160 KiB LDS) so a
// single counted vmcnt(4) per K-tile provably drains the whole next tile.
// Attention (attn4) unchanged from round 7.

#define DM   2048
#define HD   128
#define NH   16
#define LSEQ 2048
#define NB   2
#define MTOK 4096  // NB*LSEQ
#define QKVS 6144  // fused row stride

typedef __bf16 bf16x8 __attribute__((ext_vector_type(8)));
typedef float  f32x4  __attribute__((ext_vector_type(4)));

__device__ __forceinline__ unsigned short f2bf(float f) {
  unsigned u = __builtin_bit_cast(unsigned, f);
  u += 0x7fffu + ((u >> 16) & 1u);
  return (unsigned short)(u >> 16);
}
__device__ __forceinline__ unsigned packbf(float lo, float hi) {
  return (unsigned)f2bf(lo) | ((unsigned)f2bf(hi) << 16);
}
__device__ __forceinline__ float bf2f(unsigned short h) {
  unsigned u = ((unsigned)h) << 16;
  return __builtin_bit_cast(float, u);
}
__device__ __forceinline__ void gload16(const unsigned short* gc, unsigned short* l) {
  unsigned short* g = const_cast<unsigned short*>(gc);
  __builtin_amdgcn_global_load_lds((__attribute__((address_space(1))) void*)g,
                                   (__attribute__((address_space(3))) void*)l, 16, 0, 0);
}
__device__ __forceinline__ bf16x8 ld_frag(const void* p) {
  return __builtin_bit_cast(bf16x8, *(const uint4*)p);
}

// ---------------- f32 -> bf16 convert (8 elems/thread) ----------------
__global__ void cvt_bf16_k(const float* __restrict__ s, unsigned short* __restrict__ d, int n8) {
  int i = blockIdx.x * blockDim.x + threadIdx.x;
  if (i >= n8) return;
  const float4* s4 = (const float4*)s;
  float4 a = s4[2 * i], b = s4[2 * i + 1];
  uint4 o;
  o.x = packbf(a.x, a.y);
  o.y = packbf(a.z, a.w);
  o.z = packbf(b.x, b.y);
  o.w = packbf(b.z, b.w);
  ((uint4*)d)[i] = o;
}

// ---------------- bias concat [bq|bk|bv] -> f32[6144] ----------------
__global__ void bcat_k(const float* __restrict__ bq, const float* __restrict__ bk,
                       const float* __restrict__ bv, float* __restrict__ o) {
  int i = blockIdx.x * blockDim.x + threadIdx.x;
  if (i >= QKVS) return;
  float v = (i < 2048) ? bq[i] : (i < 4096) ? bk[i - 2048] : bv[i - 4096];
  o[i] = v;
}

// ============ GEMM 256x256, BK=64, 8-phase, A-dbuf + B-tribuf ============
// C[M,N] = A[M,K]*B[N,K]^T + bias. 512 threads = 8 waves (2M x 4N),
// per-wave 128x64 output (acc[8][4]). LDS = A 2x32KB + B 3x32KB = 160 KiB.
// LDS image: row stride 128B (64 bf16), 8x16B chunks/row; content at
// (row, cl) = global (row, cl ^ (row&7)); reads apply the same XOR.
template <int OUT_BF16>
__global__ __launch_bounds__(512) void gemm8p_bt(
    const unsigned short* __restrict__ A, const unsigned short* __restrict__ Bm,
    const float* __restrict__ bias, void* __restrict__ Cv, int M, int N, int K) {
  __shared__ unsigned short Ab[2][256 * 64];  // 64 KiB
  __shared__ unsigned short Bb[3][256 * 64];  // 96 KiB
  const int tid = threadIdx.x, wave = tid >> 6, lane = tid & 63;
  const int l15 = lane & 15, l4 = lane >> 4;
  const int wr = wave >> 2, wc = wave & 3;

  const int np = N >> 8;
  int n_id, m_id;
  if ((np & 7) == 0) {  // XCD-chunked when divisible
    int cpx = np >> 3;
    int xcd = blockIdx.x & 7, r = blockIdx.x >> 3;
    n_id = xcd * cpx + r % cpx;
    m_id = r / cpx;
  } else {
    n_id = blockIdx.x % np;
    m_id = blockIdx.x / np;
  }
  const size_t ra0 = (size_t)m_id * 256, rb0 = (size_t)n_id * 256;
  const int NT = K >> 6;  // BK=64 (K=2048 -> 32 tiles; needs NT>=2)

  // staging coords: half-tile = 128 rows x 8 chunks = 1024 chunks; 2 rounds.
  int srow[2], scg[2];
#pragma unroll
  for (int j = 0; j < 2; j++) {
    int c = j * 512 + tid;
    srow[j] = c >> 3;
    scg[j] = (c & 7) ^ (srow[j] & 7);  // global chunk for linear LDS slot
  }

  // stage half h (rows h*128..+127) of K-tile kt of matrix X into slot buffer
#define STAGE(Xp, rbase, kt, h, Xb, slot)                                          \
  {                                                                                \
    _Pragma("unroll") for (int j = 0; j < 2; j++) {                                \
      gload16(Xp + (rbase + (h)*128 + srow[j]) * (size_t)K + ((kt) << 6) +         \
                  scg[j] * 8,                                                      \
              &Xb[slot][(h)*8192 + (j * 512 + wave * 64) * 8]);                    \
    }                                                                              \
  }

#define LDA(mh, kh, slot)                                                          \
  _Pragma("unroll") for (int mi = 0; mi < 4; mi++) {                               \
    int row = wr * 128 + ((mh)*4 + mi) * 16 + l15;                                 \
    int cl = ((kh)*4 + l4) ^ (row & 7);                                            \
    af[mi] = ld_frag((char*)&Ab[slot][0] + row * 128 + cl * 16);                   \
  }

#define LDB(kh, slot)                                                              \
  _Pragma("unroll") for (int n = 0; n < 4; n++) {                                  \
    int row = wc * 64 + n * 16 + l15;                                              \
    int cl = ((kh)*4 + l4) ^ (row & 7);                                            \
    bfr[n] = ld_frag((char*)&Bb[slot][0] + row * 128 + cl * 16);                   \
  }

#define MMA(mh)                                                                    \
  __builtin_amdgcn_s_setprio(1);                                                   \
  _Pragma("unroll") for (int mi = 0; mi < 4; mi++)                                 \
      _Pragma("unroll") for (int n = 0; n < 4; n++)                                \
          acc[(mh)*4 + mi][n] = __builtin_amdgcn_mfma_f32_16x16x32_bf16(           \
              af[mi], bfr[n], acc[(mh)*4 + mi][n], 0, 0, 0);                       \
  __builtin_amdgcn_s_setprio(0);

#define BAR() __builtin_amdgcn_s_barrier()

  f32x4 acc[8][4] = {};
  bf16x8 af[4], bfr[4];

  // prologue: A[0]->slot0, B[0]->slot0, B[1]->slot1  (12 loads)
  STAGE(A, ra0, 0, 0, Ab, 0)
  STAGE(A, ra0, 0, 1, Ab, 0)
  STAGE(Bm, rb0, 0, 0, Bb, 0)
  STAGE(Bm, rb0, 0, 1, Bb, 0)
  STAGE(Bm, rb0, 1, 0, Bb, 1)
  STAGE(Bm, rb0, 1, 1, Bb, 1)
  asm volatile("s_waitcnt vmcnt(4)" ::: "memory");  // tile 0 (A+B) landed
  BAR();
  __builtin_amdgcn_sched_barrier(0);

  int bsc = 0;  // B slot of tile T
  for (int T = 0; T < NT; ++T) {
    __builtin_amdgcn_sched_barrier(0);  // pin tile boundary (no read hoist)
    const int ad = T & 1, an = ad ^ 1;
    int bs2 = bsc + 2;
    if (bs2 >= 3) bs2 -= 3;
    const bool pa = (T + 1 < NT), pb = (T + 2 < NT);

    // ---- P0: kh0, mh0; stage A0[T+1] ----
    LDB(0, bsc)
    LDA(0, 0, ad)
    if (pa) STAGE(A, ra0, T + 1, 0, Ab, an)
    BAR();
    MMA(0)
    BAR();
    // ---- P1: kh0, mh1; stage A1[T+1] ----
    LDA(1, 0, ad)
    if (pa) STAGE(A, ra0, T + 1, 1, Ab, an)
    BAR();
    MMA(1)
    BAR();
    // ---- P2: kh1, mh0; stage B0[T+2] ----
    LDB(1, bsc)
    LDA(0, 1, ad)
    if (pb) STAGE(Bm, rb0, T + 2, 0, Bb, bs2)
    BAR();
    MMA(0)
    BAR();
    // ---- P3: kh1, mh1; stage B1[T+2]; counted drain ----
    LDA(1, 1, ad)
    if (pb) {
      STAGE(Bm, rb0, T + 2, 1, Bb, bs2)
      asm volatile("s_waitcnt vmcnt(4)" ::: "memory");  // A[T+1]+B[T+1] landed
    } else {
      asm volatile("s_waitcnt vmcnt(0)" ::: "memory");
    }
    BAR();
    MMA(1)
    BAR();

    bsc = (bsc == 2) ? 0 : bsc + 1;
  }

  // epilogue
  const int row0 = m_id * 256 + wr * 128;
  const int col0 = n_id * 256 + wc * 64;
#pragma unroll
  for (int n = 0; n < 4; n++) {
    int col = col0 + n * 16 + l15;
    float bv = bias[col];
#pragma unroll
    for (int m = 0; m < 8; m++) {
      int rowb = row0 + m * 16 + l4 * 4;
#pragma unroll
      for (int r = 0; r < 4; r++) {
        float v = acc[m][n][r] + bv;
        if (OUT_BF16)
          ((unsigned short*)Cv)[(size_t)(rowb + r) * N + col] = f2bf(v);
        else
          ((float*)Cv)[(size_t)(rowb + r) * N + col] = v;
      }
    }
  }
#undef STAGE
#undef LDA
#undef LDB
#undef MMA
#undef BAR
}

// ------- in-place L2 normalize K rows (strided layout inside qkv) -------
__global__ void qknorm_s_k(unsigned short* __restrict__ qkv) {
  int row = blockIdx.x * 4 + (threadIdx.x >> 6);  // token*16+head
  int lane = threadIdx.x & 63;
  int t = row >> 4, h = row & 15;
  unsigned* p = (unsigned*)(qkv + (size_t)t * QKVS + 2048 + h * HD);
  unsigned w = p[lane];
  float a = bf2f((unsigned short)(w & 0xffff));
  float b = bf2f((unsigned short)(w >> 16));
  float ss = a * a + b * b;
#pragma unroll
  for (int m = 1; m < 64; m <<= 1) ss += __shfl_xor(ss, m);
  float inv = 1.0f / (sqrtf(ss) + 1e-6f);
  p[lane] = packbf(a * inv, b * inv);
}

// ---- V transpose: Vt[bh][d][l] = qkv[b,l][4096 + h*HD + d] ----
__global__ void vtrans_k(const unsigned short* __restrict__ QKV, unsigned short* __restrict__ Vt) {
  __shared__ unsigned short t[128 * 136];
  const int bh = blockIdx.y, b = bh >> 4, h = bh & 15;
  const int l0 = blockIdx.x * 128;
  const int tid = threadIdx.x;
#pragma unroll
  for (int i = 0; i < 8; i++) {
    int s = i * 256 + tid;
    int r = s >> 4, c8 = (s & 15) * 8;
    uint4 v = *(const uint4*)(QKV + ((size_t)(b * LSEQ + l0 + r)) * QKVS + 4096 + h * HD + c8);
    *(uint4*)&t[r * 136 + c8] = v;
  }
  __syncthreads();
#pragma unroll
  for (int i = 0; i < 8; i++) {
    int s = i * 256 + tid;
    int dd = s >> 4, l8 = (s & 15) * 8;
    unsigned short tmp[8];
#pragma unroll
    for (int j = 0; j < 8; j++) tmp[j] = t[(l8 + j) * 136 + dd];
    *(uint4*)(Vt + ((size_t)bh * HD + dd) * LSEQ + l0 + l8) = *(const uint4*)tmp;
  }
}

// ---------------- attention v4 (unchanged from round 7) ----------------
__global__ __launch_bounds__(256) void attn4_k(
    const unsigned short* __restrict__ QKV, const unsigned short* __restrict__ Vt,
    unsigned short* __restrict__ Na, unsigned short* __restrict__ Nb,
    float* __restrict__ Dw) {
  __shared__ __align__(16) unsigned short Ks[2][32 * 128];  // pitch 256B, XOR (row&7)<<4
  __shared__ __align__(16) unsigned short Vs[2][128 * 40];  // pitch 80B, no XOR

  const int id = blockIdx.x;
  const int xcd = id & 7, sl = id >> 3;
  const int bh = xcd * 4 + (sl >> 5);
  const int kvh = (sl >> 4) & 1, qb = sl & 15;
  const int b = bh >> 4, h = bh & 15;
  const int q0 = qb * 128;
  const int kvbase = kvh * (LSEQ / 2);
  const int tid = threadIdx.x, wave = tid >> 6, lane = tid & 63;
  const int l15 = lane & 15, l4 = lane >> 4;
  const float scale = 0.08838834764831845f;  // 1/sqrt(128)

  bf16x8 qf[2][4];
#pragma unroll
  for (int rg = 0; rg < 2; rg++) {
    const unsigned short* qp =
        QKV + ((size_t)(b * LSEQ + q0 + wave * 32 + rg * 16 + l15)) * QKVS + h * HD + l4 * 8;
    uint4 qv[4];
    float qs[4][8];
    float ss = 0.f;
#pragma unroll
    for (int kk = 0; kk < 4; kk++) qv[kk] = *(const uint4*)(qp + kk * 32);
#pragma unroll
    for (int kk = 0; kk < 4; kk++) {
      const unsigned* w = (const unsigned*)&qv[kk];
#pragma unroll
      for (int m = 0; m < 4; m++) {
        float a = bf2f((unsigned short)(w[m] & 0xffff));
        float c = bf2f((unsigned short)(w[m] >> 16));
        qs[kk][2 * m] = a; qs[kk][2 * m + 1] = c;
        ss += a * a + c * c;
      }
    }
    ss += __shfl_xor(ss, 16);
    ss += __shfl_xor(ss, 32);
    float inv = 1.0f / (sqrtf(ss) + 1e-6f);
    uint4 qo;
    unsigned* wo = (unsigned*)&qo;
#pragma unroll
    for (int kk = 0; kk < 4; kk++) {
#pragma unroll
      for (int m = 0; m < 4; m++)
        wo[m] = packbf(qs[kk][2 * m] * inv, qs[kk][2 * m + 1] * inv);
      qf[rg][kk] = __builtin_bit_cast(bf16x8, qo);
    }
  }

  f32x4 oacc[2][8] = {};
  float den[2] = {0.f, 0.f};
  uint4 pk[2], pv[2];

  const unsigned short* Kb = QKV + ((size_t)(b * LSEQ)) * QKVS + 2048 + h * HD;
  const unsigned short* Vb = Vt + ((size_t)bh * HD) * LSEQ;
  const int kr0 = tid >> 4, kc = tid & 15;
  const int vr0 = tid >> 2, vc = tid & 3;
  const int srcA = ((l4 * 2) & 3) * 16 + l15;
  const int srcB = ((l4 * 2 + 1) & 3) * 16 + l15;
  const bool hiSel = (l4 >= 2);

#pragma unroll
  for (int i = 0; i < 2; i++) {
    pk[i] = *(const uint4*)(Kb + (size_t)(kvbase + kr0 + i * 16) * QKVS + kc * 8);
    pv[i] = *(const uint4*)(Vb + (size_t)(vr0 + i * 64) * LSEQ + kvbase + vc * 8);
  }
#pragma unroll
  for (int i = 0; i < 2; i++) {
    int kr = kr0 + i * 16;
    *(uint4*)((char*)&Ks[0][0] + kr * 256 + ((kc ^ (kr & 7)) << 4)) = pk[i];
    int vr = vr0 + i * 64;
    *(uint4*)((char*)&Vs[0][0] + vr * 80 + vc * 16) = pv[i];
  }

  for (int t = 0; t < 32; t++) {
    const int cur = t & 1;
    __syncthreads();
    if (t + 1 < 32) {
      const int kvn = kvbase + (t + 1) * 32;
#pragma unroll
      for (int i = 0; i < 2; i++) {
        pk[i] = *(const uint4*)(Kb + (size_t)(kvn + kr0 + i * 16) * QKVS + kc * 8);
        pv[i] = *(const uint4*)(Vb + (size_t)(vr0 + i * 64) * LSEQ + kvn + vc * 8);
      }
    }

    f32x4 sacc[2][2] = {};
    char* ksb = (char*)&Ks[cur][0];
    __builtin_amdgcn_s_setprio(1);
#pragma unroll
    for (int ni = 0; ni < 2; ni++) {
#pragma unroll
      for (int kk = 0; kk < 4; kk++) {
        bf16x8 kf = ld_frag(ksb + (ni * 16 + l15) * 256 + (((kk * 4 + l4) ^ (l15 & 7)) << 4));
        sacc[0][ni] = __builtin_amdgcn_mfma_f32_16x16x32_bf16(kf, qf[0][kk], sacc[0][ni], 0, 0, 0);
        sacc[1][ni] = __builtin_amdgcn_mfma_f32_16x16x32_bf16(kf, qf[1][kk], sacc[1][ni], 0, 0, 0);
      }
    }
    __builtin_amdgcn_s_setprio(0);

    bf16x8 pa[2];
#pragma unroll
    for (int rg = 0; rg < 2; rg++) {
      float pe[4], po[4];
#pragma unroll
      for (int r = 0; r < 4; r++) {
        pe[r] = __expf(sacc[rg][0][r] * scale);
        po[r] = __expf(sacc[rg][1][r] * scale);
      }
      den[rg] += (pe[0] + pe[1]) + (pe[2] + pe[3]) + (po[0] + po[1]) + (po[2] + po[3]);
      unsigned c0e = packbf(pe[0], pe[1]), c1e = packbf(pe[2], pe[3]);
      unsigned c0o = packbf(po[0], po[1]), c1o = packbf(po[2], po[3]);
      unsigned a0 = __shfl(c0e, srcA), a1 = __shfl(c0o, srcA);
      unsigned b0 = __shfl(c1e, srcA), b1 = __shfl(c1o, srcA);
      unsigned c0 = __shfl(c0e, srcB), c1 = __shfl(c0o, srcB);
      unsigned d0_ = __shfl(c1e, srcB), d1 = __shfl(c1o, srcB);
      uint4 paw;
      paw.x = hiSel ? a1 : a0;
      paw.y = hiSel ? b1 : b0;
      paw.z = hiSel ? c1 : c0;
      paw.w = hiSel ? d1 : d0_;
      pa[rg] = __builtin_bit_cast(bf16x8, paw);
    }

    char* vsb = (char*)&Vs[cur][0];
    __builtin_amdgcn_s_setprio(1);
#pragma unroll
    for (int d0 = 0; d0 < 8; d0++) {
      bf16x8 vf = ld_frag(vsb + (d0 * 16 + l15) * 80 + l4 * 16);
      oacc[0][d0] = __builtin_amdgcn_mfma_f32_16x16x32_bf16(pa[0], vf, oacc[0][d0], 0, 0, 0);
      oacc[1][d0] = __builtin_amdgcn_mfma_f32_16x16x32_bf16(pa[1], vf, oacc[1][d0], 0, 0, 0);
    }
    __builtin_amdgcn_s_setprio(0);

    if (t + 1 < 32) {
      char* ksn = (char*)&Ks[cur ^ 1][0];
      char* vsn = (char*)&Vs[cur ^ 1][0];
#pragma unroll
      for (int i = 0; i < 2; i++) {
        int kr = kr0 + i * 16;
        *(uint4*)(ksn + kr * 256 + ((kc ^ (kr & 7)) << 4)) = pk[i];
        int vr = vr0 + i * 64;
        *(uint4*)(vsn + vr * 80 + vc * 16) = pv[i];
      }
    }
  }

  unsigned short* Np = kvh ? Nb : Na;
#pragma unroll
  for (int rg = 0; rg < 2; rg++) {
    float sd = den[rg];
    sd += __shfl_xor(sd, 16);
    sd += __shfl_xor(sd, 32);
    if (l4 == 0) {
      int token = b * LSEQ + q0 + wave * 32 + rg * 16 + l15;
      Dw[((size_t)kvh * MTOK + token) * NH + h] = sd;
    }
  }
#pragma unroll
  for (int rg = 0; rg < 2; rg++)
#pragma unroll
    for (int d0 = 0; d0 < 8; d0++)
#pragma unroll
      for (int r = 0; r < 4; r++) {
        int token = b * LSEQ + q0 + wave * 32 + rg * 16 + l4 * 4 + r;
        Np[(size_t)token * DM + h * HD + d0 * 16 + l15] = f2bf(oacc[rg][d0][r]);
      }
}

// ---------------- combine: ao = (n0+n1)/(d0+d1) ----------------
__global__ void comb_k(const unsigned short* __restrict__ Na,
                       const unsigned short* __restrict__ Nb,
                       const float* __restrict__ Dw, unsigned short* __restrict__ Ao) {
  int i = blockIdx.x * 256 + threadIdx.x;
  int token = i >> 8, c8 = i & 255;
  int h = c8 >> 4;
  float d = Dw[(size_t)token * NH + h] + Dw[(size_t)(MTOK + token) * NH + h];
  float inv = 1.0f / d;
  uint4 w0 = ((const uint4*)Na)[i];
  uint4 w1 = ((const uint4*)Nb)[i];
  const unsigned* a = (const unsigned*)&w0;
  const unsigned* bq = (const unsigned*)&w1;
  uint4 o;
  unsigned* ow = (unsigned*)&o;
#pragma unroll
  for (int m = 0; m < 4; m++) {
    float lo = (bf2f((unsigned short)(a[m] & 0xffff)) + bf2f((unsigned short)(bq[m] & 0xffff))) * inv;
    float hi = (bf2f((unsigned short)(a[m] >> 16)) + bf2f((unsigned short)(bq[m] >> 16))) * inv;
    ow[m] = packbf(lo, hi);
  }
  ((uint4*)Ao)[i] = o;
}

extern "C" void kernel_launch(void* const* d_in, const int* in_sizes, int n_in,
                              void* d_out, int out_size, void* d_ws, size_t ws_size,
                              hipStream_t stream) {
  const float* x  = (const float*)d_in[0];
  const float* Wq = (const float*)d_in[1];
  const float* bq = (const float*)d_in[2];
  const float* Wk = (const float*)d_in[3];
  const float* bk = (const float*)d_in[4];
  const float* Wv = (const float*)d_in[5];
  const float* bv = (const float*)d_in[6];
  const float* Wo = (const float*)d_in[7];
  const float* bo = (const float*)d_in[8];

  char* ws = (char*)d_ws;
  unsigned short* xb   = (unsigned short*)(ws + 0);          // [0,16M): x bf16 -> num partial A
  unsigned short* wqkv = (unsigned short*)(ws + 16777216);   // [16M,40M): Wq|Wk|Wv bf16
  unsigned short* wob  = (unsigned short*)(ws + 41943040);   // [40M,48M): Wo bf16
  float*          bqkv = (float*)(ws + 50331648);            // [48M,+24K)
  unsigned short* qkv  = (unsigned short*)(ws + 50364416);   // [48.03M,+48M)
  unsigned short* vt   = wqkv;                                // [16M,32M) after QKV gemm
  float*          dwp  = (float*)(ws + 33554432);            // [32M,32.5M) after QKV gemm
  unsigned short* na   = xb;                                  // [0,16M) after QKV gemm
  unsigned short* nb   = (unsigned short*)d_out;              // first 16M of d_out as scratch
  unsigned short* ao   = qkv;                                 // [48.03M,+16M) after attn

  // casts
  cvt_bf16_k<<<4096, 256, 0, stream>>>(x, xb, MTOK * DM / 8);
  cvt_bf16_k<<<2048, 256, 0, stream>>>(Wq, wqkv, DM * DM / 8);
  cvt_bf16_k<<<2048, 256, 0, stream>>>(Wk, wqkv + 2048 * 2048, DM * DM / 8);
  cvt_bf16_k<<<2048, 256, 0, stream>>>(Wv, wqkv + 4096 * 2048, DM * DM / 8);
  cvt_bf16_k<<<2048, 256, 0, stream>>>(Wo, wob, DM * DM / 8);
  bcat_k<<<24, 256, 0, stream>>>(bq, bk, bv, bqkv);

  // fused QKV projection: [4096,6144] = xb * wqkv^T + bqkv (8-phase 256^2)
  gemm8p_bt<1><<<(MTOK / 256) * (QKVS / 256), 512, 0, stream>>>(xb, wqkv, bqkv, qkv,
                                                                MTOK, QKVS, DM);

  // K-norm in place (Q-norm fused in attn)
  qknorm_s_k<<<MTOK * NH / 4, 256, 0, stream>>>(qkv);

  // V transpose per head (into dead weight buffer)
  vtrans_k<<<dim3(LSEQ / 128, NB * NH), 256, 0, stream>>>(qkv, vt);

  // attention v4 with KV-split x2
  attn4_k<<<1024, 256, 0, stream>>>(qkv, vt, na, nb, dwp);

  // combine partials -> ao (bf16)
  comb_k<<<4096, 256, 0, stream>>>(na, nb, dwp, ao);

  // output projection (f32 out, 8-phase 256^2)
  gemm8p_bt<0><<<(MTOK / 256) * (DM / 256), 512, 0, stream>>>(ao, wob, bo, (float*)d_out,
                                                              MTOK, DM, DM);
}

// Round 10
// 347.971 us; speedup vs baseline: 1.1566x; 1.0138x over previous
//
#include <hip/hip_runtime.h>

// QKNorm MHA: B=2, L=2048, D=2048, H=16, hd=128.
// Round 10: GEMM -> BM=128/BN=256/BK=64, 8 waves (64x64 each), A-dbuf +
// B-tribuf (128 KiB), ONE barrier per K-tile, counted vmcnt(4) (never 0 in
// steady state), XOR swizzle, setprio. Exact-round grids: QKV 768 blocks
// (3.0 rounds), out-proj 256 blocks (1.0 round). Attention unchanged.

#define DM   2048
#define HD   128
#define NH   16
#define LSEQ 2048
#define NB   2
#define MTOK 4096  // NB*LSEQ
#define QKVS 6144  // fused row stride

typedef __bf16 bf16x8 __attribute__((ext_vector_type(8)));
typedef float  f32x4  __attribute__((ext_vector_type(4)));

__device__ __forceinline__ unsigned short f2bf(float f) {
  unsigned u = __builtin_bit_cast(unsigned, f);
  u += 0x7fffu + ((u >> 16) & 1u);
  return (unsigned short)(u >> 16);
}
__device__ __forceinline__ unsigned packbf(float lo, float hi) {
  return (unsigned)f2bf(lo) | ((unsigned)f2bf(hi) << 16);
}
__device__ __forceinline__ float bf2f(unsigned short h) {
  unsigned u = ((unsigned)h) << 16;
  return __builtin_bit_cast(float, u);
}
__device__ __forceinline__ void gload16(const unsigned short* gc, unsigned short* l) {
  unsigned short* g = const_cast<unsigned short*>(gc);
  __builtin_amdgcn_global_load_lds((__attribute__((address_space(1))) void*)g,
                                   (__attribute__((address_space(3))) void*)l, 16, 0, 0);
}
__device__ __forceinline__ bf16x8 ld_frag(const void* p) {
  return __builtin_bit_cast(bf16x8, *(const uint4*)p);
}

// ---------------- f32 -> bf16 convert (8 elems/thread) ----------------
__global__ void cvt_bf16_k(const float* __restrict__ s, unsigned short* __restrict__ d, int n8) {
  int i = blockIdx.x * blockDim.x + threadIdx.x;
  if (i >= n8) return;
  const float4* s4 = (const float4*)s;
  float4 a = s4[2 * i], b = s4[2 * i + 1];
  uint4 o;
  o.x = packbf(a.x, a.y);
  o.y = packbf(a.z, a.w);
  o.z = packbf(b.x, b.y);
  o.w = packbf(b.z, b.w);
  ((uint4*)d)[i] = o;
}

// ---------------- bias concat [bq|bk|bv] -> f32[6144] ----------------
__global__ void bcat_k(const float* __restrict__ bq, const float* __restrict__ bk,
                       const float* __restrict__ bv, float* __restrict__ o) {
  int i = blockIdx.x * blockDim.x + threadIdx.x;
  if (i >= QKVS) return;
  float v = (i < 2048) ? bq[i] : (i < 4096) ? bk[i - 2048] : bv[i - 4096];
  o[i] = v;
}

// ========== GEMM BM=128 BN=256 BK=64, 1 barrier/K-tile, counted vmcnt ==========
// C[M,N] = A[M,K]*B[N,K]^T + bias. 512 threads = 8 waves (2M x 4N),
// per-wave 64x64 output (acc[4][4]). LDS = A 2x16KB + B 3x32KB = 128 KiB.
// LDS image: row stride 128B (8 x 16B chunks); content (row,cl) = global
// (row, cl^(row&7)); reads apply the same XOR. Conflict-free (verified r9).
template <int OUT_BF16>
__global__ __launch_bounds__(512) void gemmv3_bt(
    const unsigned short* __restrict__ A, const unsigned short* __restrict__ Bm,
    const float* __restrict__ bias, void* __restrict__ Cv, int M, int N, int K) {
  __shared__ unsigned short Ab[2][128 * 64];  // 16 KiB each
  __shared__ unsigned short Bb[3][256 * 64];  // 32 KiB each
  const int tid = threadIdx.x, wave = tid >> 6, lane = tid & 63;
  const int l15 = lane & 15, l4 = lane >> 4;
  const int wr = wave >> 2, wc = wave & 3;

  const int np = N >> 8;  // 256-wide n-panels
  int n_id, m_id;
  if ((np & 7) == 0) {  // XCD-chunked (QKV np=24, outproj np=8)
    int cpx = np >> 3;
    int xcd = blockIdx.x & 7, r = blockIdx.x >> 3;
    n_id = xcd * cpx + r % cpx;
    m_id = r / cpx;
  } else {
    n_id = blockIdx.x % np;
    m_id = blockIdx.x / np;
  }
  const size_t ra0 = (size_t)m_id * 128, rb0 = (size_t)n_id * 256;
  const int NT = K >> 6;  // BK=64; K=2048 -> 32 (needs NT>=3)

  // staging coords. A half-tile = 64 rows x 8 chunks = 1 round of 512.
  const int arow = tid >> 3, acg = (tid & 7) ^ (arow & 7);
  int brow[2], bcg[2];
#pragma unroll
  for (int j = 0; j < 2; j++) {
    int c = j * 512 + tid;
    brow[j] = c >> 3;
    bcg[j] = (c & 7) ^ (brow[j] & 7);
  }

#define STAGE_A(kt, slot)                                                       \
  {                                                                             \
    _Pragma("unroll") for (int h = 0; h < 2; h++) {                             \
      gload16(A + (ra0 + h * 64 + arow) * (size_t)K + ((kt) << 6) + acg * 8,    \
              &Ab[slot][(h * 512 + wave * 64) * 8]);                            \
    }                                                                           \
  }

#define STAGE_B(kt, slot, half)                                                 \
  {                                                                             \
    _Pragma("unroll") for (int j = 0; j < 2; j++) {                             \
      gload16(Bm + (rb0 + (half)*128 + brow[j]) * (size_t)K + ((kt) << 6) +     \
                  bcg[j] * 8,                                                   \
              &Bb[slot][((half)*1024 + j * 512 + wave * 64) * 8]);              \
    }                                                                           \
  }

#define LDA(kh, slot)                                                           \
  _Pragma("unroll") for (int mi = 0; mi < 4; mi++) {                            \
    int row = wr * 64 + mi * 16 + l15;                                          \
    int cl = ((kh)*4 + l4) ^ (row & 7);                                         \
    af[mi] = ld_frag((char*)&Ab[slot][0] + row * 128 + cl * 16);                \
  }

#define LDB(kh, slot)                                                           \
  _Pragma("unroll") for (int n = 0; n < 4; n++) {                               \
    int row = wc * 64 + n * 16 + l15;                                           \
    int cl = ((kh)*4 + l4) ^ (row & 7);                                         \
    bf_[n] = ld_frag((char*)&Bb[slot][0] + row * 128 + cl * 16);                \
  }

#define MMA()                                                                   \
  __builtin_amdgcn_s_setprio(1);                                                \
  _Pragma("unroll") for (int mi = 0; mi < 4; mi++)                              \
      _Pragma("unroll") for (int n = 0; n < 4; n++)                             \
          acc[mi][n] = __builtin_amdgcn_mfma_f32_16x16x32_bf16(                 \
              af[mi], bf_[n], acc[mi][n], 0, 0, 0);                             \
  __builtin_amdgcn_s_setprio(0);

  f32x4 acc[4][4] = {};
  bf16x8 af[4], bf_[4];

  // prologue: A[0]->a0 (2), B[0]->b0 (4), B[1]->b1 (4); drain first 6.
  STAGE_A(0, 0)
  STAGE_B(0, 0, 0)
  STAGE_B(0, 0, 1)
  STAGE_B(1, 1, 0)
  STAGE_B(1, 1, 1)
  asm volatile("s_waitcnt vmcnt(4)" ::: "memory");
  __builtin_amdgcn_s_barrier();
  __builtin_amdgcn_sched_barrier(0);

  int bsc = 0;  // B slot holding tile T
  for (int T = 0; T < NT; ++T) {
    const int ad = T & 1, an = ad ^ 1;
    int bs2 = bsc + 2;
    if (bs2 >= 3) bs2 -= 3;
    const bool pa = (T + 1 < NT), pb = (T + 2 < NT);

    if (pa) STAGE_A(T + 1, an)         // 2 gloads -> slot not read this tile
    LDB(0, bsc)
    LDA(0, ad)
    if (pb) STAGE_B(T + 2, bs2, 0)     // 2 gloads
    MMA()
    LDB(1, bsc)
    LDA(1, ad)
    if (pb) STAGE_B(T + 2, bs2, 1)     // 2 gloads
    MMA()
    if (pa) {
      if (pb) {
        asm volatile("s_waitcnt vmcnt(4)" ::: "memory");  // A[T+1]+B[T+1] in
      } else {
        asm volatile("s_waitcnt vmcnt(0)" ::: "memory");
      }
      __builtin_amdgcn_s_barrier();    // everyone done reading ad/bsc
      __builtin_amdgcn_sched_barrier(0);
    }
    bsc = (bsc == 2) ? 0 : bsc + 1;
  }

  // epilogue
  const int row0 = m_id * 128 + wr * 64;
  const int col0 = n_id * 256 + wc * 64;
#pragma unroll
  for (int n = 0; n < 4; n++) {
    int col = col0 + n * 16 + l15;
    float bv = bias[col];
#pragma unroll
    for (int mi = 0; mi < 4; mi++) {
      int rowb = row0 + mi * 16 + l4 * 4;
#pragma unroll
      for (int r = 0; r < 4; r++) {
        float v = acc[mi][n][r] + bv;
        if (OUT_BF16)
          ((unsigned short*)Cv)[(size_t)(rowb + r) * N + col] = f2bf(v);
        else
          ((float*)Cv)[(size_t)(rowb + r) * N + col] = v;
      }
    }
  }
#undef STAGE_A
#undef STAGE_B
#undef LDA
#undef LDB
#undef MMA
}

// ------- in-place L2 normalize K rows (strided layout inside qkv) -------
__global__ void qknorm_s_k(unsigned short* __restrict__ qkv) {
  int row = blockIdx.x * 4 + (threadIdx.x >> 6);  // token*16+head
  int lane = threadIdx.x & 63;
  int t = row >> 4, h = row & 15;
  unsigned* p = (unsigned*)(qkv + (size_t)t * QKVS + 2048 + h * HD);
  unsigned w = p[lane];
  float a = bf2f((unsigned short)(w & 0xffff));
  float b = bf2f((unsigned short)(w >> 16));
  float ss = a * a + b * b;
#pragma unroll
  for (int m = 1; m < 64; m <<= 1) ss += __shfl_xor(ss, m);
  float inv = 1.0f / (sqrtf(ss) + 1e-6f);
  p[lane] = packbf(a * inv, b * inv);
}

// ---- V transpose: Vt[bh][d][l] = qkv[b,l][4096 + h*HD + d] ----
__global__ void vtrans_k(const unsigned short* __restrict__ QKV, unsigned short* __restrict__ Vt) {
  __shared__ unsigned short t[128 * 136];
  const int bh = blockIdx.y, b = bh >> 4, h = bh & 15;
  const int l0 = blockIdx.x * 128;
  const int tid = threadIdx.x;
#pragma unroll
  for (int i = 0; i < 8; i++) {
    int s = i * 256 + tid;
    int r = s >> 4, c8 = (s & 15) * 8;
    uint4 v = *(const uint4*)(QKV + ((size_t)(b * LSEQ + l0 + r)) * QKVS + 4096 + h * HD + c8);
    *(uint4*)&t[r * 136 + c8] = v;
  }
  __syncthreads();
#pragma unroll
  for (int i = 0; i < 8; i++) {
    int s = i * 256 + tid;
    int dd = s >> 4, l8 = (s & 15) * 8;
    unsigned short tmp[8];
#pragma unroll
    for (int j = 0; j < 8; j++) tmp[j] = t[(l8 + j) * 136 + dd];
    *(uint4*)(Vt + ((size_t)bh * HD + dd) * LSEQ + l0 + l8) = *(const uint4*)tmp;
  }
}

// ---------------- attention v4 (unchanged from round 7) ----------------
__global__ __launch_bounds__(256) void attn4_k(
    const unsigned short* __restrict__ QKV, const unsigned short* __restrict__ Vt,
    unsigned short* __restrict__ Na, unsigned short* __restrict__ Nb,
    float* __restrict__ Dw) {
  __shared__ __align__(16) unsigned short Ks[2][32 * 128];  // pitch 256B, XOR (row&7)<<4
  __shared__ __align__(16) unsigned short Vs[2][128 * 40];  // pitch 80B, no XOR

  const int id = blockIdx.x;
  const int xcd = id & 7, sl = id >> 3;
  const int bh = xcd * 4 + (sl >> 5);
  const int kvh = (sl >> 4) & 1, qb = sl & 15;
  const int b = bh >> 4, h = bh & 15;
  const int q0 = qb * 128;
  const int kvbase = kvh * (LSEQ / 2);
  const int tid = threadIdx.x, wave = tid >> 6, lane = tid & 63;
  const int l15 = lane & 15, l4 = lane >> 4;
  const float scale = 0.08838834764831845f;  // 1/sqrt(128)

  bf16x8 qf[2][4];
#pragma unroll
  for (int rg = 0; rg < 2; rg++) {
    const unsigned short* qp =
        QKV + ((size_t)(b * LSEQ + q0 + wave * 32 + rg * 16 + l15)) * QKVS + h * HD + l4 * 8;
    uint4 qv[4];
    float qs[4][8];
    float ss = 0.f;
#pragma unroll
    for (int kk = 0; kk < 4; kk++) qv[kk] = *(const uint4*)(qp + kk * 32);
#pragma unroll
    for (int kk = 0; kk < 4; kk++) {
      const unsigned* w = (const unsigned*)&qv[kk];
#pragma unroll
      for (int m = 0; m < 4; m++) {
        float a = bf2f((unsigned short)(w[m] & 0xffff));
        float c = bf2f((unsigned short)(w[m] >> 16));
        qs[kk][2 * m] = a; qs[kk][2 * m + 1] = c;
        ss += a * a + c * c;
      }
    }
    ss += __shfl_xor(ss, 16);
    ss += __shfl_xor(ss, 32);
    float inv = 1.0f / (sqrtf(ss) + 1e-6f);
    uint4 qo;
    unsigned* wo = (unsigned*)&qo;
#pragma unroll
    for (int kk = 0; kk < 4; kk++) {
#pragma unroll
      for (int m = 0; m < 4; m++)
        wo[m] = packbf(qs[kk][2 * m] * inv, qs[kk][2 * m + 1] * inv);
      qf[rg][kk] = __builtin_bit_cast(bf16x8, qo);
    }
  }

  f32x4 oacc[2][8] = {};
  float den[2] = {0.f, 0.f};
  uint4 pk[2], pv[2];

  const unsigned short* Kb = QKV + ((size_t)(b * LSEQ)) * QKVS + 2048 + h * HD;
  const unsigned short* Vb = Vt + ((size_t)bh * HD) * LSEQ;
  const int kr0 = tid >> 4, kc = tid & 15;
  const int vr0 = tid >> 2, vc = tid & 3;
  const int srcA = ((l4 * 2) & 3) * 16 + l15;
  const int srcB = ((l4 * 2 + 1) & 3) * 16 + l15;
  const bool hiSel = (l4 >= 2);

#pragma unroll
  for (int i = 0; i < 2; i++) {
    pk[i] = *(const uint4*)(Kb + (size_t)(kvbase + kr0 + i * 16) * QKVS + kc * 8);
    pv[i] = *(const uint4*)(Vb + (size_t)(vr0 + i * 64) * LSEQ + kvbase + vc * 8);
  }
#pragma unroll
  for (int i = 0; i < 2; i++) {
    int kr = kr0 + i * 16;
    *(uint4*)((char*)&Ks[0][0] + kr * 256 + ((kc ^ (kr & 7)) << 4)) = pk[i];
    int vr = vr0 + i * 64;
    *(uint4*)((char*)&Vs[0][0] + vr * 80 + vc * 16) = pv[i];
  }

  for (int t = 0; t < 32; t++) {
    const int cur = t & 1;
    __syncthreads();
    if (t + 1 < 32) {
      const int kvn = kvbase + (t + 1) * 32;
#pragma unroll
      for (int i = 0; i < 2; i++) {
        pk[i] = *(const uint4*)(Kb + (size_t)(kvn + kr0 + i * 16) * QKVS + kc * 8);
        pv[i] = *(const uint4*)(Vb + (size_t)(vr0 + i * 64) * LSEQ + kvn + vc * 8);
      }
    }

    f32x4 sacc[2][2] = {};
    char* ksb = (char*)&Ks[cur][0];
    __builtin_amdgcn_s_setprio(1);
#pragma unroll
    for (int ni = 0; ni < 2; ni++) {
#pragma unroll
      for (int kk = 0; kk < 4; kk++) {
        bf16x8 kf = ld_frag(ksb + (ni * 16 + l15) * 256 + (((kk * 4 + l4) ^ (l15 & 7)) << 4));
        sacc[0][ni] = __builtin_amdgcn_mfma_f32_16x16x32_bf16(kf, qf[0][kk], sacc[0][ni], 0, 0, 0);
        sacc[1][ni] = __builtin_amdgcn_mfma_f32_16x16x32_bf16(kf, qf[1][kk], sacc[1][ni], 0, 0, 0);
      }
    }
    __builtin_amdgcn_s_setprio(0);

    bf16x8 pa[2];
#pragma unroll
    for (int rg = 0; rg < 2; rg++) {
      float pe[4], po[4];
#pragma unroll
      for (int r = 0; r < 4; r++) {
        pe[r] = __expf(sacc[rg][0][r] * scale);
        po[r] = __expf(sacc[rg][1][r] * scale);
      }
      den[rg] += (pe[0] + pe[1]) + (pe[2] + pe[3]) + (po[0] + po[1]) + (po[2] + po[3]);
      unsigned c0e = packbf(pe[0], pe[1]), c1e = packbf(pe[2], pe[3]);
      unsigned c0o = packbf(po[0], po[1]), c1o = packbf(po[2], po[3]);
      unsigned a0 = __shfl(c0e, srcA), a1 = __shfl(c0o, srcA);
      unsigned b0 = __shfl(c1e, srcA), b1 = __shfl(c1o, srcA);
      unsigned c0 = __shfl(c0e, srcB), c1 = __shfl(c0o, srcB);
      unsigned d0_ = __shfl(c1e, srcB), d1 = __shfl(c1o, srcB);
      uint4 paw;
      paw.x = hiSel ? a1 : a0;
      paw.y = hiSel ? b1 : b0;
      paw.z = hiSel ? c1 : c0;
      paw.w = hiSel ? d1 : d0_;
      pa[rg] = __builtin_bit_cast(bf16x8, paw);
    }

    char* vsb = (char*)&Vs[cur][0];
    __builtin_amdgcn_s_setprio(1);
#pragma unroll
    for (int d0 = 0; d0 < 8; d0++) {
      bf16x8 vf = ld_frag(vsb + (d0 * 16 + l15) * 80 + l4 * 16);
      oacc[0][d0] = __builtin_amdgcn_mfma_f32_16x16x32_bf16(pa[0], vf, oacc[0][d0], 0, 0, 0);
      oacc[1][d0] = __builtin_amdgcn_mfma_f32_16x16x32_bf16(pa[1], vf, oacc[1][d0], 0, 0, 0);
    }
    __builtin_amdgcn_s_setprio(0);

    if (t + 1 < 32) {
      char* ksn = (char*)&Ks[cur ^ 1][0];
      char* vsn = (char*)&Vs[cur ^ 1][0];
#pragma unroll
      for (int i = 0; i < 2; i++) {
        int kr = kr0 + i * 16;
        *(uint4*)(ksn + kr * 256 + ((kc ^ (kr & 7)) << 4)) = pk[i];
        int vr = vr0 + i * 64;
        *(uint4*)(vsn + vr * 80 + vc * 16) = pv[i];
      }
    }
  }

  unsigned short* Np = kvh ? Nb : Na;
#pragma unroll
  for (int rg = 0; rg < 2; rg++) {
    float sd = den[rg];
    sd += __shfl_xor(sd, 16);
    sd += __shfl_xor(sd, 32);
    if (l4 == 0) {
      int token = b * LSEQ + q0 + wave * 32 + rg * 16 + l15;
      Dw[((size_t)kvh * MTOK + token) * NH + h] = sd;
    }
  }
#pragma unroll
  for (int rg = 0; rg < 2; rg++)
#pragma unroll
    for (int d0 = 0; d0 < 8; d0++)
#pragma unroll
      for (int r = 0; r < 4; r++) {
        int token = b * LSEQ + q0 + wave * 32 + rg * 16 + l4 * 4 + r;
        Np[(size_t)token * DM + h * HD + d0 * 16 + l15] = f2bf(oacc[rg][d0][r]);
      }
}

// ---------------- combine: ao = (n0+n1)/(d0+d1) ----------------
__global__ void comb_k(const unsigned short* __restrict__ Na,
                       const unsigned short* __restrict__ Nb,
                       const float* __restrict__ Dw, unsigned short* __restrict__ Ao) {
  int i = blockIdx.x * 256 + threadIdx.x;
  int token = i >> 8, c8 = i & 255;
  int h = c8 >> 4;
  float d = Dw[(size_t)token * NH + h] + Dw[(size_t)(MTOK + token) * NH + h];
  float inv = 1.0f / d;
  uint4 w0 = ((const uint4*)Na)[i];
  uint4 w1 = ((const uint4*)Nb)[i];
  const unsigned* a = (const unsigned*)&w0;
  const unsigned* bq = (const unsigned*)&w1;
  uint4 o;
  unsigned* ow = (unsigned*)&o;
#pragma unroll
  for (int m = 0; m < 4; m++) {
    float lo = (bf2f((unsigned short)(a[m] & 0xffff)) + bf2f((unsigned short)(bq[m] & 0xffff))) * inv;
    float hi = (bf2f((unsigned short)(a[m] >> 16)) + bf2f((unsigned short)(bq[m] >> 16))) * inv;
    ow[m] = packbf(lo, hi);
  }
  ((uint4*)Ao)[i] = o;
}

extern "C" void kernel_launch(void* const* d_in, const int* in_sizes, int n_in,
                              void* d_out, int out_size, void* d_ws, size_t ws_size,
                              hipStream_t stream) {
  const float* x  = (const float*)d_in[0];
  const float* Wq = (const float*)d_in[1];
  const float* bq = (const float*)d_in[2];
  const float* Wk = (const float*)d_in[3];
  const float* bk = (const float*)d_in[4];
  const float* Wv = (const float*)d_in[5];
  const float* bv = (const float*)d_in[6];
  const float* Wo = (const float*)d_in[7];
  const float* bo = (const float*)d_in[8];

  char* ws = (char*)d_ws;
  unsigned short* xb   = (unsigned short*)(ws + 0);          // [0,16M): x bf16 -> num partial A
  unsigned short* wqkv = (unsigned short*)(ws + 16777216);   // [16M,40M): Wq|Wk|Wv bf16
  unsigned short* wob  = (unsigned short*)(ws + 41943040);   // [40M,48M): Wo bf16
  float*          bqkv = (float*)(ws + 50331648);            // [48M,+24K)
  unsigned short* qkv  = (unsigned short*)(ws + 50364416);   // [48.03M,+48M)
  unsigned short* vt   = wqkv;                                // [16M,32M) after QKV gemm
  float*          dwp  = (float*)(ws + 33554432);            // [32M,32.5M) after QKV gemm
  unsigned short* na   = xb;                                  // [0,16M) after QKV gemm
  unsigned short* nb   = (unsigned short*)d_out;              // first 16M of d_out as scratch
  unsigned short* ao   = qkv;                                 // [48.03M,+16M) after attn

  // casts
  cvt_bf16_k<<<4096, 256, 0, stream>>>(x, xb, MTOK * DM / 8);
  cvt_bf16_k<<<2048, 256, 0, stream>>>(Wq, wqkv, DM * DM / 8);
  cvt_bf16_k<<<2048, 256, 0, stream>>>(Wk, wqkv + 2048 * 2048, DM * DM / 8);
  cvt_bf16_k<<<2048, 256, 0, stream>>>(Wv, wqkv + 4096 * 2048, DM * DM / 8);
  cvt_bf16_k<<<2048, 256, 0, stream>>>(Wo, wob, DM * DM / 8);
  bcat_k<<<24, 256, 0, stream>>>(bq, bk, bv, bqkv);

  // fused QKV projection: [4096,6144] = xb * wqkv^T + bqkv  (768 blocks, 3 rounds)
  gemmv3_bt<1><<<(MTOK / 128) * (QKVS / 256), 512, 0, stream>>>(xb, wqkv, bqkv, qkv,
                                                                MTOK, QKVS, DM);

  // K-norm in place (Q-norm fused in attn)
  qknorm_s_k<<<MTOK * NH / 4, 256, 0, stream>>>(qkv);

  // V transpose per head (into dead weight buffer)
  vtrans_k<<<dim3(LSEQ / 128, NB * NH), 256, 0, stream>>>(qkv, vt);

  // attention v4 with KV-split x2
  attn4_k<<<1024, 256, 0, stream>>>(qkv, vt, na, nb, dwp);

  // combine partials -> ao (bf16)
  comb_k<<<4096, 256, 0, stream>>>(na, nb, dwp, ao);

  // output projection (f32 out, 256 blocks = 1.0 round)
  gemmv3_bt<0><<<(MTOK / 128) * (DM / 256), 512, 0, stream>>>(ao, wob, bo, (float*)d_out,
                                                              MTOK, DM, DM);
}

// Round 11
// 322.110 us; speedup vs baseline: 1.2495x; 1.0803x over previous
//
#include <hip/hip_runtime.h>

// QKNorm MHA: B=2, L=2048, D=2048, H=16, hd=128.
// Round 11: glue fused into GEMM — QKV GEMM epilogue does q/k L2-norm
// (f32-exact, cross-wave LDS reduce) and writes V transposed straight to
// Vt[bh][d][l] (deletes qknorm + vtrans kernels); all casts in ONE kernel;
// bias region-select inline (deletes bcat). 5 launches total.
// GEMM core = round-10 gemmv3 (measured best). Attention = round-7 attn4
// minus the now-redundant Q-norm.

#define DM   2048
#define HD   128
#define NH   16
#define LSEQ 2048
#define NB   2
#define MTOK 4096  // NB*LSEQ
#define QKVS 6144  // fused row stride

typedef __bf16 bf16x8 __attribute__((ext_vector_type(8)));
typedef float  f32x4  __attribute__((ext_vector_type(4)));

__device__ __forceinline__ unsigned short f2bf(float f) {
  unsigned u = __builtin_bit_cast(unsigned, f);
  u += 0x7fffu + ((u >> 16) & 1u);
  return (unsigned short)(u >> 16);
}
__device__ __forceinline__ unsigned packbf(float lo, float hi) {
  return (unsigned)f2bf(lo) | ((unsigned)f2bf(hi) << 16);
}
__device__ __forceinline__ float bf2f(unsigned short h) {
  unsigned u = ((unsigned)h) << 16;
  return __builtin_bit_cast(float, u);
}
__device__ __forceinline__ void gload16(const unsigned short* gc, unsigned short* l) {
  unsigned short* g = const_cast<unsigned short*>(gc);
  __builtin_amdgcn_global_load_lds((__attribute__((address_space(1))) void*)g,
                                   (__attribute__((address_space(3))) void*)l, 16, 0, 0);
}
__device__ __forceinline__ bf16x8 ld_frag(const void* p) {
  return __builtin_bit_cast(bf16x8, *(const uint4*)p);
}

// ------ fused f32->bf16 cast: x, Wq, Wk, Wv, Wo in one launch ------
__global__ void cvtall_k(const float* __restrict__ x, const float* __restrict__ Wq,
                         const float* __restrict__ Wk, const float* __restrict__ Wv,
                         const float* __restrict__ Wo, unsigned short* __restrict__ xb,
                         unsigned short* __restrict__ wqkv, unsigned short* __restrict__ wob) {
  const int xc = MTOK * DM / 8;    // 1048576
  const int per = DM * DM / 8;     // 524288
  int i = blockIdx.x * blockDim.x + threadIdx.x;
  const float* s;
  unsigned short* d;
  int j;
  if (i < xc) { s = x; d = xb; j = i; }
  else if (i < xc + per) { s = Wq; d = wqkv; j = i - xc; }
  else if (i < xc + 2 * per) { s = Wk; d = wqkv + DM * DM; j = i - xc - per; }
  else if (i < xc + 3 * per) { s = Wv; d = wqkv + 2 * DM * DM; j = i - xc - 2 * per; }
  else { s = Wo; d = wob; j = i - xc - 3 * per; }
  const float4* s4 = (const float4*)s;
  float4 a = s4[2 * j], b = s4[2 * j + 1];
  uint4 o;
  o.x = packbf(a.x, a.y);
  o.y = packbf(a.z, a.w);
  o.z = packbf(b.x, b.y);
  o.w = packbf(b.z, b.w);
  ((uint4*)d)[j] = o;
}

// ========== GEMM BM=128 BN=256 BK=64 (round-10 core, measured 138us) ==========
// QKVMODE=1: panels n_id<16 get fused per-head L2-norm (q,k); panels n_id>=16
// are V: written TRANSPOSED to Vt[bh][d][l] (packed 8B stores). Bias picked
// by region from b0/b1/b2. QKVMODE=0: plain store with bias b0.
template <int OUT_BF16, int QKVMODE>
__global__ __launch_bounds__(512) void gemmv3_bt(
    const unsigned short* __restrict__ A, const unsigned short* __restrict__ Bm,
    const float* __restrict__ b0, const float* __restrict__ b1,
    const float* __restrict__ b2, void* __restrict__ Cv,
    unsigned short* __restrict__ Vt, int M, int N, int K) {
  __shared__ unsigned short Ab[2][128 * 64];  // 16 KiB each
  __shared__ unsigned short Bb[3][256 * 64];  // 32 KiB each
  const int tid = threadIdx.x, wave = tid >> 6, lane = tid & 63;
  const int l15 = lane & 15, l4 = lane >> 4;
  const int wr = wave >> 2, wc = wave & 3;

  const int np = N >> 8;
  int n_id, m_id;
  if ((np & 7) == 0) {
    int cpx = np >> 3;
    int xcd = blockIdx.x & 7, r = blockIdx.x >> 3;
    n_id = xcd * cpx + r % cpx;
    m_id = r / cpx;
  } else {
    n_id = blockIdx.x % np;
    m_id = blockIdx.x / np;
  }
  const size_t ra0 = (size_t)m_id * 128, rb0 = (size_t)n_id * 256;
  const int NT = K >> 6;

  const int arow = tid >> 3, acg = (tid & 7) ^ (arow & 7);
  int brow[2], bcg[2];
#pragma unroll
  for (int j = 0; j < 2; j++) {
    int c = j * 512 + tid;
    brow[j] = c >> 3;
    bcg[j] = (c & 7) ^ (brow[j] & 7);
  }

#define STAGE_A(kt, slot)                                                       \
  {                                                                             \
    _Pragma("unroll") for (int h = 0; h < 2; h++) {                             \
      gload16(A + (ra0 + h * 64 + arow) * (size_t)K + ((kt) << 6) + acg * 8,    \
              &Ab[slot][(h * 512 + wave * 64) * 8]);                            \
    }                                                                           \
  }

#define STAGE_B(kt, slot, half)                                                 \
  {                                                                             \
    _Pragma("unroll") for (int j = 0; j < 2; j++) {                             \
      gload16(Bm + (rb0 + (half)*128 + brow[j]) * (size_t)K + ((kt) << 6) +     \
                  bcg[j] * 8,                                                   \
              &Bb[slot][((half)*1024 + j * 512 + wave * 64) * 8]);              \
    }                                                                           \
  }

#define LDA(kh, slot)                                                           \
  _Pragma("unroll") for (int mi = 0; mi < 4; mi++) {                            \
    int row = wr * 64 + mi * 16 + l15;                                          \
    int cl = ((kh)*4 + l4) ^ (row & 7);                                         \
    af[mi] = ld_frag((char*)&Ab[slot][0] + row * 128 + cl * 16);                \
  }

#define LDB(kh, slot)                                                           \
  _Pragma("unroll") for (int n = 0; n < 4; n++) {                               \
    int row = wc * 64 + n * 16 + l15;                                           \
    int cl = ((kh)*4 + l4) ^ (row & 7);                                         \
    bf_[n] = ld_frag((char*)&Bb[slot][0] + row * 128 + cl * 16);                \
  }

#define MMA()                                                                   \
  __builtin_amdgcn_s_setprio(1);                                                \
  _Pragma("unroll") for (int mi = 0; mi < 4; mi++)                              \
      _Pragma("unroll") for (int n = 0; n < 4; n++)                             \
          acc[mi][n] = __builtin_amdgcn_mfma_f32_16x16x32_bf16(                 \
              af[mi], bf_[n], acc[mi][n], 0, 0, 0);                             \
  __builtin_amdgcn_s_setprio(0);

  f32x4 acc[4][4] = {};
  bf16x8 af[4], bf_[4];

  STAGE_A(0, 0)
  STAGE_B(0, 0, 0)
  STAGE_B(0, 0, 1)
  STAGE_B(1, 1, 0)
  STAGE_B(1, 1, 1)
  asm volatile("s_waitcnt vmcnt(4)" ::: "memory");
  __builtin_amdgcn_s_barrier();
  __builtin_amdgcn_sched_barrier(0);

  int bsc = 0;
  for (int T = 0; T < NT; ++T) {
    const int ad = T & 1, an = ad ^ 1;
    int bs2 = bsc + 2;
    if (bs2 >= 3) bs2 -= 3;
    const bool pa = (T + 1 < NT), pb = (T + 2 < NT);

    if (pa) STAGE_A(T + 1, an)
    LDB(0, bsc)
    LDA(0, ad)
    if (pb) STAGE_B(T + 2, bs2, 0)
    MMA()
    LDB(1, bsc)
    LDA(1, ad)
    if (pb) STAGE_B(T + 2, bs2, 1)
    MMA()
    if (pa) {
      if (pb) {
        asm volatile("s_waitcnt vmcnt(4)" ::: "memory");
      } else {
        asm volatile("s_waitcnt vmcnt(0)" ::: "memory");
      }
      __builtin_amdgcn_s_barrier();
      __builtin_amdgcn_sched_barrier(0);
    }
    bsc = (bsc == 2) ? 0 : bsc + 1;
  }

  // ---------------- epilogue ----------------
  const int row0 = m_id * 128 + wr * 64;
  const int col0 = n_id * 256 + wc * 64;

  // bias per n (region-select for QKV mode)
  float bv[4];
#pragma unroll
  for (int n = 0; n < 4; n++) {
    int col = col0 + n * 16 + l15;
    if (QKVMODE)
      bv[n] = col < 2048 ? b0[col] : (col < 4096 ? b1[col - 2048] : b2[col - 4096]);
    else
      bv[n] = b0[col];
  }

  if (QKVMODE && n_id >= 16) {
    // V panel -> Vt[bh][d][l], packed 8B stores (4 consecutive l per lane)
    const int bblk = row0 >> 11;  // batch (BM=128 never straddles L boundary)
#pragma unroll
    for (int n = 0; n < 4; n++) {
      int vcol = col0 + n * 16 + l15 - 4096;
      int hh = vcol >> 7, dd = vcol & 127;
      size_t vbase = ((size_t)(bblk * 16 + hh) * 128 + dd) * (size_t)LSEQ;
#pragma unroll
      for (int mi = 0; mi < 4; mi++) {
        int rowb = row0 + mi * 16 + l4 * 4;
        unsigned short t4[4];
#pragma unroll
        for (int r = 0; r < 4; r++) t4[r] = f2bf(acc[mi][n][r] + bv[n]);
        *(uint2*)(Vt + vbase + (rowb & (LSEQ - 1))) = *(const uint2*)t4;
      }
    }
    return;
  }

  if (QKVMODE && n_id < 16) {
    // fused per-head (128-col) L2 norm over q/k, f32-exact, then bf16 store
    float* sp = (float*)&Ab[0][0];  // [8 waves][64 rows]
    __syncthreads();                // all K-loop LDS reads long done
#pragma unroll
    for (int mi = 0; mi < 4; mi++) {
#pragma unroll
      for (int r = 0; r < 4; r++) {
        float ss = 0.f;
#pragma unroll
        for (int n = 0; n < 4; n++) {
          float v = acc[mi][n][r] + bv[n];
          ss += v * v;
        }
        ss += __shfl_xor(ss, 1);
        ss += __shfl_xor(ss, 2);
        ss += __shfl_xor(ss, 4);
        ss += __shfl_xor(ss, 8);
        if (l15 == 0) sp[wave * 64 + mi * 16 + l4 * 4 + r] = ss;
      }
    }
    __syncthreads();
#pragma unroll
    for (int mi = 0; mi < 4; mi++) {
#pragma unroll
      for (int r = 0; r < 4; r++) {
        int idx = mi * 16 + l4 * 4 + r;
        float ss = sp[wave * 64 + idx] + sp[(wave ^ 1) * 64 + idx];
        float inv = 1.0f / (sqrtf(ss) + 1e-6f);
        int row = row0 + mi * 16 + l4 * 4 + r;
#pragma unroll
        for (int n = 0; n < 4; n++) {
          int col = col0 + n * 16 + l15;
          ((unsigned short*)Cv)[(size_t)row * N + col] = f2bf((acc[mi][n][r] + bv[n]) * inv);
        }
      }
    }
    return;
  }

  // plain store (out-proj)
#pragma unroll
  for (int n = 0; n < 4; n++) {
    int col = col0 + n * 16 + l15;
#pragma unroll
    for (int mi = 0; mi < 4; mi++) {
      int rowb = row0 + mi * 16 + l4 * 4;
#pragma unroll
      for (int r = 0; r < 4; r++) {
        float v = acc[mi][n][r] + bv[n];
        if (OUT_BF16)
          ((unsigned short*)Cv)[(size_t)(rowb + r) * N + col] = f2bf(v);
        else
          ((float*)Cv)[(size_t)(rowb + r) * N + col] = v;
      }
    }
  }
#undef STAGE_A
#undef STAGE_B
#undef LDA
#undef LDB
#undef MMA
}

// ---------------- attention v4 (round-7 core; Q pre-normalized) ----------------
__global__ __launch_bounds__(256) void attn4_k(
    const unsigned short* __restrict__ QKV, const unsigned short* __restrict__ Vt,
    unsigned short* __restrict__ Na, unsigned short* __restrict__ Nb,
    float* __restrict__ Dw) {
  __shared__ __align__(16) unsigned short Ks[2][32 * 128];  // pitch 256B, XOR (row&7)<<4
  __shared__ __align__(16) unsigned short Vs[2][128 * 40];  // pitch 80B, no XOR

  const int id = blockIdx.x;
  const int xcd = id & 7, sl = id >> 3;
  const int bh = xcd * 4 + (sl >> 5);
  const int kvh = (sl >> 4) & 1, qb = sl & 15;
  const int b = bh >> 4, h = bh & 15;
  const int q0 = qb * 128;
  const int kvbase = kvh * (LSEQ / 2);
  const int tid = threadIdx.x, wave = tid >> 6, lane = tid & 63;
  const int l15 = lane & 15, l4 = lane >> 4;
  const float scale = 0.08838834764831845f;  // 1/sqrt(128)

  // Q (normalized in GEMM epilogue): plain fragment loads
  bf16x8 qf[2][4];
#pragma unroll
  for (int rg = 0; rg < 2; rg++) {
    const unsigned short* qp =
        QKV + ((size_t)(b * LSEQ + q0 + wave * 32 + rg * 16 + l15)) * QKVS + h * HD + l4 * 8;
#pragma unroll
    for (int kk = 0; kk < 4; kk++) qf[rg][kk] = ld_frag(qp + kk * 32);
  }

  f32x4 oacc[2][8] = {};
  float den[2] = {0.f, 0.f};
  uint4 pk[2], pv[2];

  const unsigned short* Kb = QKV + ((size_t)(b * LSEQ)) * QKVS + 2048 + h * HD;
  const unsigned short* Vb = Vt + ((size_t)bh * HD) * LSEQ;
  const int kr0 = tid >> 4, kc = tid & 15;
  const int vr0 = tid >> 2, vc = tid & 3;
  const int srcA = ((l4 * 2) & 3) * 16 + l15;
  const int srcB = ((l4 * 2 + 1) & 3) * 16 + l15;
  const bool hiSel = (l4 >= 2);

#pragma unroll
  for (int i = 0; i < 2; i++) {
    pk[i] = *(const uint4*)(Kb + (size_t)(kvbase + kr0 + i * 16) * QKVS + kc * 8);
    pv[i] = *(const uint4*)(Vb + (size_t)(vr0 + i * 64) * LSEQ + kvbase + vc * 8);
  }
#pragma unroll
  for (int i = 0; i < 2; i++) {
    int kr = kr0 + i * 16;
    *(uint4*)((char*)&Ks[0][0] + kr * 256 + ((kc ^ (kr & 7)) << 4)) = pk[i];
    int vr = vr0 + i * 64;
    *(uint4*)((char*)&Vs[0][0] + vr * 80 + vc * 16) = pv[i];
  }

  for (int t = 0; t < 32; t++) {
    const int cur = t & 1;
    __syncthreads();
    if (t + 1 < 32) {
      const int kvn = kvbase + (t + 1) * 32;
#pragma unroll
      for (int i = 0; i < 2; i++) {
        pk[i] = *(const uint4*)(Kb + (size_t)(kvn + kr0 + i * 16) * QKVS + kc * 8);
        pv[i] = *(const uint4*)(Vb + (size_t)(vr0 + i * 64) * LSEQ + kvn + vc * 8);
      }
    }

    f32x4 sacc[2][2] = {};
    char* ksb = (char*)&Ks[cur][0];
    __builtin_amdgcn_s_setprio(1);
#pragma unroll
    for (int ni = 0; ni < 2; ni++) {
#pragma unroll
      for (int kk = 0; kk < 4; kk++) {
        bf16x8 kf = ld_frag(ksb + (ni * 16 + l15) * 256 + (((kk * 4 + l4) ^ (l15 & 7)) << 4));
        sacc[0][ni] = __builtin_amdgcn_mfma_f32_16x16x32_bf16(kf, qf[0][kk], sacc[0][ni], 0, 0, 0);
        sacc[1][ni] = __builtin_amdgcn_mfma_f32_16x16x32_bf16(kf, qf[1][kk], sacc[1][ni], 0, 0, 0);
      }
    }
    __builtin_amdgcn_s_setprio(0);

    bf16x8 pa[2];
#pragma unroll
    for (int rg = 0; rg < 2; rg++) {
      float pe[4], po[4];
#pragma unroll
      for (int r = 0; r < 4; r++) {
        pe[r] = __expf(sacc[rg][0][r] * scale);
        po[r] = __expf(sacc[rg][1][r] * scale);
      }
      den[rg] += (pe[0] + pe[1]) + (pe[2] + pe[3]) + (po[0] + po[1]) + (po[2] + po[3]);
      unsigned c0e = packbf(pe[0], pe[1]), c1e = packbf(pe[2], pe[3]);
      unsigned c0o = packbf(po[0], po[1]), c1o = packbf(po[2], po[3]);
      unsigned a0 = __shfl(c0e, srcA), a1 = __shfl(c0o, srcA);
      unsigned b0 = __shfl(c1e, srcA), b1 = __shfl(c1o, srcA);
      unsigned c0 = __shfl(c0e, srcB), c1 = __shfl(c0o, srcB);
      unsigned d0_ = __shfl(c1e, srcB), d1 = __shfl(c1o, srcB);
      uint4 paw;
      paw.x = hiSel ? a1 : a0;
      paw.y = hiSel ? b1 : b0;
      paw.z = hiSel ? c1 : c0;
      paw.w = hiSel ? d1 : d0_;
      pa[rg] = __builtin_bit_cast(bf16x8, paw);
    }

    char* vsb = (char*)&Vs[cur][0];
    __builtin_amdgcn_s_setprio(1);
#pragma unroll
    for (int d0 = 0; d0 < 8; d0++) {
      bf16x8 vf = ld_frag(vsb + (d0 * 16 + l15) * 80 + l4 * 16);
      oacc[0][d0] = __builtin_amdgcn_mfma_f32_16x16x32_bf16(pa[0], vf, oacc[0][d0], 0, 0, 0);
      oacc[1][d0] = __builtin_amdgcn_mfma_f32_16x16x32_bf16(pa[1], vf, oacc[1][d0], 0, 0, 0);
    }
    __builtin_amdgcn_s_setprio(0);

    if (t + 1 < 32) {
      char* ksn = (char*)&Ks[cur ^ 1][0];
      char* vsn = (char*)&Vs[cur ^ 1][0];
#pragma unroll
      for (int i = 0; i < 2; i++) {
        int kr = kr0 + i * 16;
        *(uint4*)(ksn + kr * 256 + ((kc ^ (kr & 7)) << 4)) = pk[i];
        int vr = vr0 + i * 64;
        *(uint4*)(vsn + vr * 80 + vc * 16) = pv[i];
      }
    }
  }

  unsigned short* Np = kvh ? Nb : Na;
#pragma unroll
  for (int rg = 0; rg < 2; rg++) {
    float sd = den[rg];
    sd += __shfl_xor(sd, 16);
    sd += __shfl_xor(sd, 32);
    if (l4 == 0) {
      int token = b * LSEQ + q0 + wave * 32 + rg * 16 + l15;
      Dw[((size_t)kvh * MTOK + token) * NH + h] = sd;
    }
  }
#pragma unroll
  for (int rg = 0; rg < 2; rg++)
#pragma unroll
    for (int d0 = 0; d0 < 8; d0++)
#pragma unroll
      for (int r = 0; r < 4; r++) {
        int token = b * LSEQ + q0 + wave * 32 + rg * 16 + l4 * 4 + r;
        Np[(size_t)token * DM + h * HD + d0 * 16 + l15] = f2bf(oacc[rg][d0][r]);
      }
}

// ---------------- combine: ao = (n0+n1)/(d0+d1) ----------------
__global__ void comb_k(const unsigned short* __restrict__ Na,
                       const unsigned short* __restrict__ Nb,
                       const float* __restrict__ Dw, unsigned short* __restrict__ Ao) {
  int i = blockIdx.x * 256 + threadIdx.x;
  int token = i >> 8, c8 = i & 255;
  int h = c8 >> 4;
  float d = Dw[(size_t)token * NH + h] + Dw[(size_t)(MTOK + token) * NH + h];
  float inv = 1.0f / d;
  uint4 w0 = ((const uint4*)Na)[i];
  uint4 w1 = ((const uint4*)Nb)[i];
  const unsigned* a = (const unsigned*)&w0;
  const unsigned* bq = (const unsigned*)&w1;
  uint4 o;
  unsigned* ow = (unsigned*)&o;
#pragma unroll
  for (int m = 0; m < 4; m++) {
    float lo = (bf2f((unsigned short)(a[m] & 0xffff)) + bf2f((unsigned short)(bq[m] & 0xffff))) * inv;
    float hi = (bf2f((unsigned short)(a[m] >> 16)) + bf2f((unsigned short)(bq[m] >> 16))) * inv;
    ow[m] = packbf(lo, hi);
  }
  ((uint4*)Ao)[i] = o;
}

extern "C" void kernel_launch(void* const* d_in, const int* in_sizes, int n_in,
                              void* d_out, int out_size, void* d_ws, size_t ws_size,
                              hipStream_t stream) {
  const float* x  = (const float*)d_in[0];
  const float* Wq = (const float*)d_in[1];
  const float* bq = (const float*)d_in[2];
  const float* Wk = (const float*)d_in[3];
  const float* bk = (const float*)d_in[4];
  const float* Wv = (const float*)d_in[5];
  const float* bv = (const float*)d_in[6];
  const float* Wo = (const float*)d_in[7];
  const float* bo = (const float*)d_in[8];

  char* ws = (char*)d_ws;
  unsigned short* xb   = (unsigned short*)(ws + 0);          // [0,16M): x bf16 -> num partial A
  unsigned short* wqkv = (unsigned short*)(ws + 16777216);   // [16M,40M): Wq|Wk|Wv bf16
  unsigned short* wob  = (unsigned short*)(ws + 41943040);   // [40M,48M): Wo bf16
  unsigned short* qkv  = (unsigned short*)(ws + 50364416);   // 48 MB (q/k used; v region unused)
  unsigned short* vt   = (unsigned short*)(ws + 100696064);  // 16.8 MB (GEMM writes transposed V)
  float*          dwp  = (float*)(ws + 16777216);            // alias wqkv (dead after QKV gemm)
  unsigned short* na   = xb;                                  // alias xb (x dead after QKV gemm)
  unsigned short* nb   = (unsigned short*)d_out;              // d_out as scratch until out-proj
  unsigned short* ao   = qkv;                                 // alias qkv base after attn

  // 1. all casts in one launch
  cvtall_k<<<12288, 256, 0, stream>>>(x, Wq, Wk, Wv, Wo, xb, wqkv, wob);

  // 2. fused QKV projection + q/k-norm + transposed V  (768 blocks, 3 rounds)
  gemmv3_bt<1, 1><<<(MTOK / 128) * (QKVS / 256), 512, 0, stream>>>(
      xb, wqkv, bq, bk, bv, qkv, vt, MTOK, QKVS, DM);

  // 3. attention (KV-split x2)
  attn4_k<<<1024, 256, 0, stream>>>(qkv, vt, na, nb, dwp);

  // 4. combine partials -> ao (bf16)
  comb_k<<<4096, 256, 0, stream>>>(na, nb, dwp, ao);

  // 5. output projection (f32 out, 256 blocks)
  gemmv3_bt<0, 0><<<(MTOK / 128) * (DM / 256), 512, 0, stream>>>(
      ao, wob, bo, bo, bo, (float*)d_out, nullptr, MTOK, DM, DM);
}

// Round 12
// 312.304 us; speedup vs baseline: 1.2887x; 1.0314x over previous
//
#include <hip/hip_runtime.h>

// QKNorm MHA: B=2, L=2048, D=2048, H=16, hd=128.
// Round 12: GEMM re-parameterized for CROSS-BLOCK OVERLAP: BM=128, BN=128,
// BK=64, 256 threads (4 waves, 64x64 each), A-dbuf + B-tribuf = 80 KiB LDS
// -> 2 blocks/CU (two independent barrier groups hide each other's stalls),
// counted vmcnt(4) schedule (never 0 in steady state), XOR swizzle, fused
// q/k-norm + transposed-V epilogue. Grids exact: QKV 1536 (3.0 rounds @2/CU),
// outproj 512 (1.0). cvtall / attn4 / comb unchanged.

#define DM   2048
#define HD   128
#define NH   16
#define LSEQ 2048
#define NB   2
#define MTOK 4096  // NB*LSEQ
#define QKVS 6144  // fused row stride

typedef __bf16 bf16x8 __attribute__((ext_vector_type(8)));
typedef float  f32x4  __attribute__((ext_vector_type(4)));

__device__ __forceinline__ unsigned short f2bf(float f) {
  unsigned u = __builtin_bit_cast(unsigned, f);
  u += 0x7fffu + ((u >> 16) & 1u);
  return (unsigned short)(u >> 16);
}
__device__ __forceinline__ unsigned packbf(float lo, float hi) {
  return (unsigned)f2bf(lo) | ((unsigned)f2bf(hi) << 16);
}
__device__ __forceinline__ float bf2f(unsigned short h) {
  unsigned u = ((unsigned)h) << 16;
  return __builtin_bit_cast(float, u);
}
__device__ __forceinline__ void gload16(const unsigned short* gc, unsigned short* l) {
  unsigned short* g = const_cast<unsigned short*>(gc);
  __builtin_amdgcn_global_load_lds((__attribute__((address_space(1))) void*)g,
                                   (__attribute__((address_space(3))) void*)l, 16, 0, 0);
}
__device__ __forceinline__ bf16x8 ld_frag(const void* p) {
  return __builtin_bit_cast(bf16x8, *(const uint4*)p);
}

// ------ fused f32->bf16 cast: x, Wq, Wk, Wv, Wo in one launch ------
__global__ void cvtall_k(const float* __restrict__ x, const float* __restrict__ Wq,
                         const float* __restrict__ Wk, const float* __restrict__ Wv,
                         const float* __restrict__ Wo, unsigned short* __restrict__ xb,
                         unsigned short* __restrict__ wqkv, unsigned short* __restrict__ wob) {
  const int xc = MTOK * DM / 8;    // 1048576
  const int per = DM * DM / 8;     // 524288
  int i = blockIdx.x * blockDim.x + threadIdx.x;
  const float* s;
  unsigned short* d;
  int j;
  if (i < xc) { s = x; d = xb; j = i; }
  else if (i < xc + per) { s = Wq; d = wqkv; j = i - xc; }
  else if (i < xc + 2 * per) { s = Wk; d = wqkv + DM * DM; j = i - xc - per; }
  else if (i < xc + 3 * per) { s = Wv; d = wqkv + 2 * DM * DM; j = i - xc - 2 * per; }
  else { s = Wo; d = wob; j = i - xc - 3 * per; }
  const float4* s4 = (const float4*)s;
  float4 a = s4[2 * j], b = s4[2 * j + 1];
  uint4 o;
  o.x = packbf(a.x, a.y);
  o.y = packbf(a.z, a.w);
  o.z = packbf(b.x, b.y);
  o.w = packbf(b.z, b.w);
  ((uint4*)d)[j] = o;
}

// ========== GEMM BM=128 BN=128 BK=64, 256 thr, 2 blocks/CU ==========
// QKVMODE=1: panels n_id<32 (q|k) get fused per-head L2-norm; n_id>=32 are V,
// written TRANSPOSED to Vt[bh][d][l]. Bias region-select. QKVMODE=0: plain.
template <int OUT_BF16, int QKVMODE>
__global__ __launch_bounds__(256) void gemmv4_bt(
    const unsigned short* __restrict__ A, const unsigned short* __restrict__ Bm,
    const float* __restrict__ b0, const float* __restrict__ b1,
    const float* __restrict__ b2, void* __restrict__ Cv,
    unsigned short* __restrict__ Vt, int M, int N, int K) {
  __shared__ unsigned short Ab[2][128 * 64];  // 16 KiB each
  __shared__ unsigned short Bb[3][128 * 64];  // 16 KiB each  (total 80 KiB)
  const int tid = threadIdx.x, wave = tid >> 6, lane = tid & 63;
  const int l15 = lane & 15, l4 = lane >> 4;
  const int wr = wave >> 1, wc = wave & 1;  // 2M x 2N waves, 64x64 each

  const int np = N >> 7;  // 128-wide n-panels
  int n_id, m_id;
  if ((np & 7) == 0) {  // XCD-chunked (QKV np=48, outproj np=16)
    int cpx = np >> 3;
    int xcd = blockIdx.x & 7, r = blockIdx.x >> 3;
    n_id = xcd * cpx + r % cpx;
    m_id = r / cpx;
  } else {
    n_id = blockIdx.x % np;
    m_id = blockIdx.x / np;
  }
  const size_t ra0 = (size_t)m_id * 128, rb0 = (size_t)n_id * 128;
  const int NT = K >> 6;  // BK=64; K=2048 -> 32

  // staging coords: tile = 128 rows x 8 chunks = 1024 chunks = 4 rounds of 256
  int srow[4], scg[4];
#pragma unroll
  for (int j = 0; j < 4; j++) {
    int c = j * 256 + tid;
    srow[j] = c >> 3;
    scg[j] = (c & 7) ^ (srow[j] & 7);
  }

#define STAGE_A(kt, slot)                                                       \
  {                                                                             \
    _Pragma("unroll") for (int j = 0; j < 4; j++) {                             \
      gload16(A + (ra0 + srow[j]) * (size_t)K + ((kt) << 6) + scg[j] * 8,       \
              &Ab[slot][(j * 256 + wave * 64) * 8]);                            \
    }                                                                           \
  }

#define STAGE_B01(kt, slot)                                                     \
  {                                                                             \
    _Pragma("unroll") for (int j = 0; j < 2; j++) {                             \
      gload16(Bm + (rb0 + srow[j]) * (size_t)K + ((kt) << 6) + scg[j] * 8,      \
              &Bb[slot][(j * 256 + wave * 64) * 8]);                            \
    }                                                                           \
  }

#define STAGE_B23(kt, slot)                                                     \
  {                                                                             \
    _Pragma("unroll") for (int j = 2; j < 4; j++) {                             \
      gload16(Bm + (rb0 + srow[j]) * (size_t)K + ((kt) << 6) + scg[j] * 8,      \
              &Bb[slot][(j * 256 + wave * 64) * 8]);                            \
    }                                                                           \
  }

#define LDA(kh, slot)                                                           \
  _Pragma("unroll") for (int mi = 0; mi < 4; mi++) {                            \
    int row = wr * 64 + mi * 16 + l15;                                          \
    int cl = ((kh)*4 + l4) ^ (row & 7);                                         \
    af[mi] = ld_frag((char*)&Ab[slot][0] + row * 128 + cl * 16);                \
  }

#define LDB(kh, slot)                                                           \
  _Pragma("unroll") for (int n = 0; n < 4; n++) {                               \
    int row = wc * 64 + n * 16 + l15;                                           \
    int cl = ((kh)*4 + l4) ^ (row & 7);                                         \
    bf_[n] = ld_frag((char*)&Bb[slot][0] + row * 128 + cl * 16);                \
  }

#define MMA()                                                                   \
  __builtin_amdgcn_s_setprio(1);                                                \
  _Pragma("unroll") for (int mi = 0; mi < 4; mi++)                              \
      _Pragma("unroll") for (int n = 0; n < 4; n++)                             \
          acc[mi][n] = __builtin_amdgcn_mfma_f32_16x16x32_bf16(                 \
              af[mi], bf_[n], acc[mi][n], 0, 0, 0);                             \
  __builtin_amdgcn_s_setprio(0);

  f32x4 acc[4][4] = {};
  bf16x8 af[4], bf_[4];

  // prologue: A[0]->a0, B[0]->b0, B[1]->b1 (12 loads); drain oldest 8.
  STAGE_A(0, 0)
  STAGE_B01(0, 0)
  STAGE_B23(0, 0)
  STAGE_B01(1, 1)
  STAGE_B23(1, 1)
  asm volatile("s_waitcnt vmcnt(4)" ::: "memory");
  __builtin_amdgcn_s_barrier();
  __builtin_amdgcn_sched_barrier(0);

  int bsc = 0;
  for (int T = 0; T < NT; ++T) {
    const int ad = T & 1, an = ad ^ 1;
    int bs2 = bsc + 2;
    if (bs2 >= 3) bs2 -= 3;
    const bool pa = (T + 1 < NT), pb = (T + 2 < NT);

    if (pa) STAGE_A(T + 1, an)
    LDB(0, bsc)
    LDA(0, ad)
    if (pb) STAGE_B01(T + 2, bs2)
    MMA()
    LDB(1, bsc)
    LDA(1, ad)
    if (pb) STAGE_B23(T + 2, bs2)
    MMA()
    if (pa) {
      if (pb) {
        asm volatile("s_waitcnt vmcnt(4)" ::: "memory");  // A[T+1]+B[T+1] in
      } else {
        asm volatile("s_waitcnt vmcnt(0)" ::: "memory");
      }
      __builtin_amdgcn_s_barrier();
      __builtin_amdgcn_sched_barrier(0);
    }
    bsc = (bsc == 2) ? 0 : bsc + 1;
  }

  // ---------------- epilogue ----------------
  const int row0 = m_id * 128 + wr * 64;
  const int col0 = n_id * 128 + wc * 64;

  float bv[4];
#pragma unroll
  for (int n = 0; n < 4; n++) {
    int col = col0 + n * 16 + l15;
    if (QKVMODE)
      bv[n] = col < 2048 ? b0[col] : (col < 4096 ? b1[col - 2048] : b2[col - 4096]);
    else
      bv[n] = b0[col];
  }

  if (QKVMODE && n_id >= 32) {
    // V panel -> Vt[bh][d][l], packed 8B stores
    const int bblk = (m_id * 128) >> 11;
#pragma unroll
    for (int n = 0; n < 4; n++) {
      int vcol = col0 + n * 16 + l15 - 4096;
      int hh = vcol >> 7, dd = vcol & 127;
      size_t vbase = ((size_t)(bblk * 16 + hh) * 128 + dd) * (size_t)LSEQ;
#pragma unroll
      for (int mi = 0; mi < 4; mi++) {
        int rowb = row0 + mi * 16 + l4 * 4;
        unsigned short t4[4];
#pragma unroll
        for (int r = 0; r < 4; r++) t4[r] = f2bf(acc[mi][n][r] + bv[n]);
        *(uint2*)(Vt + vbase + (rowb & (LSEQ - 1))) = *(const uint2*)t4;
      }
    }
    return;
  }

  if (QKVMODE && n_id < 32) {
    // fused per-head L2 norm: block spans exactly one 128-col head
    float* sp = (float*)&Ab[0][0];  // [2 wc][128 rows]
    __syncthreads();
#pragma unroll
    for (int mi = 0; mi < 4; mi++) {
#pragma unroll
      for (int r = 0; r < 4; r++) {
        float ss = 0.f;
#pragma unroll
        for (int n = 0; n < 4; n++) {
          float v = acc[mi][n][r] + bv[n];
          ss += v * v;
        }
        ss += __shfl_xor(ss, 1);
        ss += __shfl_xor(ss, 2);
        ss += __shfl_xor(ss, 4);
        ss += __shfl_xor(ss, 8);
        if (l15 == 0) sp[wc * 128 + wr * 64 + mi * 16 + l4 * 4 + r] = ss;
      }
    }
    __syncthreads();
#pragma unroll
    for (int mi = 0; mi < 4; mi++) {
#pragma unroll
      for (int r = 0; r < 4; r++) {
        int idx = wr * 64 + mi * 16 + l4 * 4 + r;
        float ss = sp[idx] + sp[128 + idx];
        float inv = 1.0f / (sqrtf(ss) + 1e-6f);
        int row = m_id * 128 + idx;
#pragma unroll
        for (int n = 0; n < 4; n++) {
          int col = col0 + n * 16 + l15;
          ((unsigned short*)Cv)[(size_t)row * N + col] = f2bf((acc[mi][n][r] + bv[n]) * inv);
        }
      }
    }
    return;
  }

  // plain store (out-proj)
#pragma unroll
  for (int n = 0; n < 4; n++) {
    int col = col0 + n * 16 + l15;
#pragma unroll
    for (int mi = 0; mi < 4; mi++) {
      int rowb = row0 + mi * 16 + l4 * 4;
#pragma unroll
      for (int r = 0; r < 4; r++) {
        float v = acc[mi][n][r] + bv[n];
        if (OUT_BF16)
          ((unsigned short*)Cv)[(size_t)(rowb + r) * N + col] = f2bf(v);
        else
          ((float*)Cv)[(size_t)(rowb + r) * N + col] = v;
      }
    }
  }
#undef STAGE_A
#undef STAGE_B01
#undef STAGE_B23
#undef LDA
#undef LDB
#undef MMA
}

// ---------------- attention v4 (round-7 core; Q pre-normalized) ----------------
__global__ __launch_bounds__(256) void attn4_k(
    const unsigned short* __restrict__ QKV, const unsigned short* __restrict__ Vt,
    unsigned short* __restrict__ Na, unsigned short* __restrict__ Nb,
    float* __restrict__ Dw) {
  __shared__ __align__(16) unsigned short Ks[2][32 * 128];  // pitch 256B, XOR (row&7)<<4
  __shared__ __align__(16) unsigned short Vs[2][128 * 40];  // pitch 80B, no XOR

  const int id = blockIdx.x;
  const int xcd = id & 7, sl = id >> 3;
  const int bh = xcd * 4 + (sl >> 5);
  const int kvh = (sl >> 4) & 1, qb = sl & 15;
  const int b = bh >> 4, h = bh & 15;
  const int q0 = qb * 128;
  const int kvbase = kvh * (LSEQ / 2);
  const int tid = threadIdx.x, wave = tid >> 6, lane = tid & 63;
  const int l15 = lane & 15, l4 = lane >> 4;
  const float scale = 0.08838834764831845f;  // 1/sqrt(128)

  bf16x8 qf[2][4];
#pragma unroll
  for (int rg = 0; rg < 2; rg++) {
    const unsigned short* qp =
        QKV + ((size_t)(b * LSEQ + q0 + wave * 32 + rg * 16 + l15)) * QKVS + h * HD + l4 * 8;
#pragma unroll
    for (int kk = 0; kk < 4; kk++) qf[rg][kk] = ld_frag(qp + kk * 32);
  }

  f32x4 oacc[2][8] = {};
  float den[2] = {0.f, 0.f};
  uint4 pk[2], pv[2];

  const unsigned short* Kb = QKV + ((size_t)(b * LSEQ)) * QKVS + 2048 + h * HD;
  const unsigned short* Vb = Vt + ((size_t)bh * HD) * LSEQ;
  const int kr0 = tid >> 4, kc = tid & 15;
  const int vr0 = tid >> 2, vc = tid & 3;
  const int srcA = ((l4 * 2) & 3) * 16 + l15;
  const int srcB = ((l4 * 2 + 1) & 3) * 16 + l15;
  const bool hiSel = (l4 >= 2);

#pragma unroll
  for (int i = 0; i < 2; i++) {
    pk[i] = *(const uint4*)(Kb + (size_t)(kvbase + kr0 + i * 16) * QKVS + kc * 8);
    pv[i] = *(const uint4*)(Vb + (size_t)(vr0 + i * 64) * LSEQ + kvbase + vc * 8);
  }
#pragma unroll
  for (int i = 0; i < 2; i++) {
    int kr = kr0 + i * 16;
    *(uint4*)((char*)&Ks[0][0] + kr * 256 + ((kc ^ (kr & 7)) << 4)) = pk[i];
    int vr = vr0 + i * 64;
    *(uint4*)((char*)&Vs[0][0] + vr * 80 + vc * 16) = pv[i];
  }

  for (int t = 0; t < 32; t++) {
    const int cur = t & 1;
    __syncthreads();
    if (t + 1 < 32) {
      const int kvn = kvbase + (t + 1) * 32;
#pragma unroll
      for (int i = 0; i < 2; i++) {
        pk[i] = *(const uint4*)(Kb + (size_t)(kvn + kr0 + i * 16) * QKVS + kc * 8);
        pv[i] = *(const uint4*)(Vb + (size_t)(vr0 + i * 64) * LSEQ + kvn + vc * 8);
      }
    }

    f32x4 sacc[2][2] = {};
    char* ksb = (char*)&Ks[cur][0];
    __builtin_amdgcn_s_setprio(1);
#pragma unroll
    for (int ni = 0; ni < 2; ni++) {
#pragma unroll
      for (int kk = 0; kk < 4; kk++) {
        bf16x8 kf = ld_frag(ksb + (ni * 16 + l15) * 256 + (((kk * 4 + l4) ^ (l15 & 7)) << 4));
        sacc[0][ni] = __builtin_amdgcn_mfma_f32_16x16x32_bf16(kf, qf[0][kk], sacc[0][ni], 0, 0, 0);
        sacc[1][ni] = __builtin_amdgcn_mfma_f32_16x16x32_bf16(kf, qf[1][kk], sacc[1][ni], 0, 0, 0);
      }
    }
    __builtin_amdgcn_s_setprio(0);

    bf16x8 pa[2];
#pragma unroll
    for (int rg = 0; rg < 2; rg++) {
      float pe[4], po[4];
#pragma unroll
      for (int r = 0; r < 4; r++) {
        pe[r] = __expf(sacc[rg][0][r] * scale);
        po[r] = __expf(sacc[rg][1][r] * scale);
      }
      den[rg] += (pe[0] + pe[1]) + (pe[2] + pe[3]) + (po[0] + po[1]) + (po[2] + po[3]);
      unsigned c0e = packbf(pe[0], pe[1]), c1e = packbf(pe[2], pe[3]);
      unsigned c0o = packbf(po[0], po[1]), c1o = packbf(po[2], po[3]);
      unsigned a0 = __shfl(c0e, srcA), a1 = __shfl(c0o, srcA);
      unsigned b0 = __shfl(c1e, srcA), b1 = __shfl(c1o, srcA);
      unsigned c0 = __shfl(c0e, srcB), c1 = __shfl(c0o, srcB);
      unsigned d0_ = __shfl(c1e, srcB), d1 = __shfl(c1o, srcB);
      uint4 paw;
      paw.x = hiSel ? a1 : a0;
      paw.y = hiSel ? b1 : b0;
      paw.z = hiSel ? c1 : c0;
      paw.w = hiSel ? d1 : d0_;
      pa[rg] = __builtin_bit_cast(bf16x8, paw);
    }

    char* vsb = (char*)&Vs[cur][0];
    __builtin_amdgcn_s_setprio(1);
#pragma unroll
    for (int d0 = 0; d0 < 8; d0++) {
      bf16x8 vf = ld_frag(vsb + (d0 * 16 + l15) * 80 + l4 * 16);
      oacc[0][d0] = __builtin_amdgcn_mfma_f32_16x16x32_bf16(pa[0], vf, oacc[0][d0], 0, 0, 0);
      oacc[1][d0] = __builtin_amdgcn_mfma_f32_16x16x32_bf16(pa[1], vf, oacc[1][d0], 0, 0, 0);
    }
    __builtin_amdgcn_s_setprio(0);

    if (t + 1 < 32) {
      char* ksn = (char*)&Ks[cur ^ 1][0];
      char* vsn = (char*)&Vs[cur ^ 1][0];
#pragma unroll
      for (int i = 0; i < 2; i++) {
        int kr = kr0 + i * 16;
        *(uint4*)(ksn + kr * 256 + ((kc ^ (kr & 7)) << 4)) = pk[i];
        int vr = vr0 + i * 64;
        *(uint4*)(vsn + vr * 80 + vc * 16) = pv[i];
      }
    }
  }

  unsigned short* Np = kvh ? Nb : Na;
#pragma unroll
  for (int rg = 0; rg < 2; rg++) {
    float sd = den[rg];
    sd += __shfl_xor(sd, 16);
    sd += __shfl_xor(sd, 32);
    if (l4 == 0) {
      int token = b * LSEQ + q0 + wave * 32 + rg * 16 + l15;
      Dw[((size_t)kvh * MTOK + token) * NH + h] = sd;
    }
  }
#pragma unroll
  for (int rg = 0; rg < 2; rg++)
#pragma unroll
    for (int d0 = 0; d0 < 8; d0++)
#pragma unroll
      for (int r = 0; r < 4; r++) {
        int token = b * LSEQ + q0 + wave * 32 + rg * 16 + l4 * 4 + r;
        Np[(size_t)token * DM + h * HD + d0 * 16 + l15] = f2bf(oacc[rg][d0][r]);
      }
}

// ---------------- combine: ao = (n0+n1)/(d0+d1) ----------------
__global__ void comb_k(const unsigned short* __restrict__ Na,
                       const unsigned short* __restrict__ Nb,
                       const float* __restrict__ Dw, unsigned short* __restrict__ Ao) {
  int i = blockIdx.x * 256 + threadIdx.x;
  int token = i >> 8, c8 = i & 255;
  int h = c8 >> 4;
  float d = Dw[(size_t)token * NH + h] + Dw[(size_t)(MTOK + token) * NH + h];
  float inv = 1.0f / d;
  uint4 w0 = ((const uint4*)Na)[i];
  uint4 w1 = ((const uint4*)Nb)[i];
  const unsigned* a = (const unsigned*)&w0;
  const unsigned* bq = (const unsigned*)&w1;
  uint4 o;
  unsigned* ow = (unsigned*)&o;
#pragma unroll
  for (int m = 0; m < 4; m++) {
    float lo = (bf2f((unsigned short)(a[m] & 0xffff)) + bf2f((unsigned short)(bq[m] & 0xffff))) * inv;
    float hi = (bf2f((unsigned short)(a[m] >> 16)) + bf2f((unsigned short)(bq[m] >> 16))) * inv;
    ow[m] = packbf(lo, hi);
  }
  ((uint4*)Ao)[i] = o;
}

extern "C" void kernel_launch(void* const* d_in, const int* in_sizes, int n_in,
                              void* d_out, int out_size, void* d_ws, size_t ws_size,
                              hipStream_t stream) {
  const float* x  = (const float*)d_in[0];
  const float* Wq = (const float*)d_in[1];
  const float* bq = (const float*)d_in[2];
  const float* Wk = (const float*)d_in[3];
  const float* bk = (const float*)d_in[4];
  const float* Wv = (const float*)d_in[5];
  const float* bv = (const float*)d_in[6];
  const float* Wo = (const float*)d_in[7];
  const float* bo = (const float*)d_in[8];

  char* ws = (char*)d_ws;
  unsigned short* xb   = (unsigned short*)(ws + 0);          // [0,16M): x bf16 -> num partial A
  unsigned short* wqkv = (unsigned short*)(ws + 16777216);   // [16M,40M): Wq|Wk|Wv bf16
  unsigned short* wob  = (unsigned short*)(ws + 41943040);   // [40M,48M): Wo bf16
  unsigned short* qkv  = (unsigned short*)(ws + 50364416);   // 48 MB region (q|k cols used)
  unsigned short* vt   = (unsigned short*)(ws + 100696064);  // 16.8 MB (transposed V)
  float*          dwp  = (float*)(ws + 16777216);            // alias wqkv (dead after QKV gemm)
  unsigned short* na   = xb;                                  // alias xb
  unsigned short* nb   = (unsigned short*)d_out;              // d_out as scratch until out-proj
  unsigned short* ao   = qkv;                                 // alias qkv base after attn

  // 1. all casts in one launch
  cvtall_k<<<12288, 256, 0, stream>>>(x, Wq, Wk, Wv, Wo, xb, wqkv, wob);

  // 2. fused QKV projection + q/k-norm + transposed V (1536 blocks, 3 rounds @2/CU)
  gemmv4_bt<1, 1><<<(MTOK / 128) * (QKVS / 128), 256, 0, stream>>>(
      xb, wqkv, bq, bk, bv, qkv, vt, MTOK, QKVS, DM);

  // 3. attention (KV-split x2)
  attn4_k<<<1024, 256, 0, stream>>>(qkv, vt, na, nb, dwp);

  // 4. combine partials -> ao (bf16)
  comb_k<<<4096, 256, 0, stream>>>(na, nb, dwp, ao);

  // 5. output projection (f32 out, 512 blocks = 1.0 round @2/CU)
  gemmv4_bt<0, 0><<<(MTOK / 128) * (DM / 128), 256, 0, stream>>>(
      ao, wob, bo, bo, bo, (float*)d_out, nullptr, MTOK, DM, DM);
}

// Round 13
// 292.289 us; speedup vs baseline: 1.3769x; 1.0685x over previous
//
#include <hip/hip_runtime.h>

// QKNorm MHA: B=2, L=2048, D=2048, H=16, hd=128.
// Round 13: r11 kernel with the GEMM inner loop switched to the fine-phase
// schedule (r9-style): per K-tile 2 phases of {8 ds_read; stage; s_barrier;
// lgkmcnt(0); sched_barrier; 16 MFMA}, tile-boundary counted vmcnt(4).
// Tail-free grids kept (QKV 768 = 3.0 rounds, outproj 256 = 1.0).
// Epilogue fusions (q/k-norm, transposed V), cvtall, attn4, comb unchanged.

#define DM   2048
#define HD   128
#define NH   16
#define LSEQ 2048
#define NB   2
#define MTOK 4096  // NB*LSEQ
#define QKVS 6144  // fused row stride

typedef __bf16 bf16x8 __attribute__((ext_vector_type(8)));
typedef float  f32x4  __attribute__((ext_vector_type(4)));

__device__ __forceinline__ unsigned short f2bf(float f) {
  unsigned u = __builtin_bit_cast(unsigned, f);
  u += 0x7fffu + ((u >> 16) & 1u);
  return (unsigned short)(u >> 16);
}
__device__ __forceinline__ unsigned packbf(float lo, float hi) {
  return (unsigned)f2bf(lo) | ((unsigned)f2bf(hi) << 16);
}
__device__ __forceinline__ float bf2f(unsigned short h) {
  unsigned u = ((unsigned)h) << 16;
  return __builtin_bit_cast(float, u);
}
__device__ __forceinline__ void gload16(const unsigned short* gc, unsigned short* l) {
  unsigned short* g = const_cast<unsigned short*>(gc);
  __builtin_amdgcn_global_load_lds((__attribute__((address_space(1))) void*)g,
                                   (__attribute__((address_space(3))) void*)l, 16, 0, 0);
}
__device__ __forceinline__ bf16x8 ld_frag(const void* p) {
  return __builtin_bit_cast(bf16x8, *(const uint4*)p);
}

// ------ fused f32->bf16 cast: x, Wq, Wk, Wv, Wo in one launch ------
__global__ void cvtall_k(const float* __restrict__ x, const float* __restrict__ Wq,
                         const float* __restrict__ Wk, const float* __restrict__ Wv,
                         const float* __restrict__ Wo, unsigned short* __restrict__ xb,
                         unsigned short* __restrict__ wqkv, unsigned short* __restrict__ wob) {
  const int xc = MTOK * DM / 8;    // 1048576
  const int per = DM * DM / 8;     // 524288
  int i = blockIdx.x * blockDim.x + threadIdx.x;
  const float* s;
  unsigned short* d;
  int j;
  if (i < xc) { s = x; d = xb; j = i; }
  else if (i < xc + per) { s = Wq; d = wqkv; j = i - xc; }
  else if (i < xc + 2 * per) { s = Wk; d = wqkv + DM * DM; j = i - xc - per; }
  else if (i < xc + 3 * per) { s = Wv; d = wqkv + 2 * DM * DM; j = i - xc - 2 * per; }
  else { s = Wo; d = wob; j = i - xc - 3 * per; }
  const float4* s4 = (const float4*)s;
  float4 a = s4[2 * j], b = s4[2 * j + 1];
  uint4 o;
  o.x = packbf(a.x, a.y);
  o.y = packbf(a.z, a.w);
  o.z = packbf(b.x, b.y);
  o.w = packbf(b.z, b.w);
  ((uint4*)d)[j] = o;
}

// ========== GEMM BM=128 BN=256 BK=64, fine-phase, counted vmcnt ==========
// QKVMODE=1: panels n_id<16 fused per-head L2-norm (q,k); n_id>=16 = V,
// written TRANSPOSED to Vt[bh][d][l]. Bias region-select. QKVMODE=0: plain.
template <int OUT_BF16, int QKVMODE>
__global__ __launch_bounds__(512) void gemmv5_bt(
    const unsigned short* __restrict__ A, const unsigned short* __restrict__ Bm,
    const float* __restrict__ b0, const float* __restrict__ b1,
    const float* __restrict__ b2, void* __restrict__ Cv,
    unsigned short* __restrict__ Vt, int M, int N, int K) {
  __shared__ unsigned short Ab[2][128 * 64];  // 16 KiB each
  __shared__ unsigned short Bb[3][256 * 64];  // 32 KiB each (128 KiB total)
  const int tid = threadIdx.x, wave = tid >> 6, lane = tid & 63;
  const int l15 = lane & 15, l4 = lane >> 4;
  const int wr = wave >> 2, wc = wave & 3;

  const int np = N >> 8;
  int n_id, m_id;
  if ((np & 7) == 0) {
    int cpx = np >> 3;
    int xcd = blockIdx.x & 7, r = blockIdx.x >> 3;
    n_id = xcd * cpx + r % cpx;
    m_id = r / cpx;
  } else {
    n_id = blockIdx.x % np;
    m_id = blockIdx.x / np;
  }
  const size_t ra0 = (size_t)m_id * 128, rb0 = (size_t)n_id * 256;
  const int NT = K >> 6;

  const int arow = tid >> 3, acg = (tid & 7) ^ (arow & 7);
  int brow[2], bcg[2];
#pragma unroll
  for (int j = 0; j < 2; j++) {
    int c = j * 512 + tid;
    brow[j] = c >> 3;
    bcg[j] = (c & 7) ^ (brow[j] & 7);
  }

#define STAGE_A(kt, slot)                                                       \
  {                                                                             \
    _Pragma("unroll") for (int h = 0; h < 2; h++) {                             \
      gload16(A + (ra0 + h * 64 + arow) * (size_t)K + ((kt) << 6) + acg * 8,    \
              &Ab[slot][(h * 512 + wave * 64) * 8]);                            \
    }                                                                           \
  }

#define STAGE_B(kt, slot, half)                                                 \
  {                                                                             \
    _Pragma("unroll") for (int j = 0; j < 2; j++) {                             \
      gload16(Bm + (rb0 + (half)*128 + brow[j]) * (size_t)K + ((kt) << 6) +     \
                  bcg[j] * 8,                                                   \
              &Bb[slot][((half)*1024 + j * 512 + wave * 64) * 8]);              \
    }                                                                           \
  }

#define LDA(kh, slot)                                                           \
  _Pragma("unroll") for (int mi = 0; mi < 4; mi++) {                            \
    int row = wr * 64 + mi * 16 + l15;                                          \
    int cl = ((kh)*4 + l4) ^ (row & 7);                                         \
    af[mi] = ld_frag((char*)&Ab[slot][0] + row * 128 + cl * 16);                \
  }

#define LDB(kh, slot)                                                           \
  _Pragma("unroll") for (int n = 0; n < 4; n++) {                               \
    int row = wc * 64 + n * 16 + l15;                                           \
    int cl = ((kh)*4 + l4) ^ (row & 7);                                         \
    bf_[n] = ld_frag((char*)&Bb[slot][0] + row * 128 + cl * 16);                \
  }

#define MMA()                                                                   \
  __builtin_amdgcn_s_setprio(1);                                                \
  _Pragma("unroll") for (int mi = 0; mi < 4; mi++)                              \
      _Pragma("unroll") for (int n = 0; n < 4; n++)                             \
          acc[mi][n] = __builtin_amdgcn_mfma_f32_16x16x32_bf16(                 \
              af[mi], bf_[n], acc[mi][n], 0, 0, 0);                             \
  __builtin_amdgcn_s_setprio(0);

  f32x4 acc[4][4] = {};
  bf16x8 af[4], bf_[4];

  // prologue: A[0]->a0 (2), B[0]->b0 (4), B[1]->b1 (4); drain first 6.
  STAGE_A(0, 0)
  STAGE_B(0, 0, 0)
  STAGE_B(0, 0, 1)
  STAGE_B(1, 1, 0)
  STAGE_B(1, 1, 1)
  asm volatile("s_waitcnt vmcnt(4)" ::: "memory");
  __builtin_amdgcn_s_barrier();
  __builtin_amdgcn_sched_barrier(0);

  int bsc = 0;  // B slot holding tile T
  for (int T = 0; T < NT; ++T) {
    const int ad = T & 1, an = ad ^ 1;
    int bs2 = bsc + 2;
    if (bs2 >= 3) bs2 -= 3;
    const bool pa = (T + 1 < NT), pb = (T + 2 < NT);

    // ---- phase 0: kh=0 reads; stage A(T+1); barrier; MFMA ----
    LDB(0, bsc)
    LDA(0, ad)
    if (pa) STAGE_A(T + 1, an)
    __builtin_amdgcn_s_barrier();
    asm volatile("s_waitcnt lgkmcnt(0)" ::: "memory");
    __builtin_amdgcn_sched_barrier(0);
    MMA()
    __builtin_amdgcn_s_barrier();
    // ---- phase 1: kh=1 reads; stage B(T+2); barrier; MFMA ----
    LDB(1, bsc)
    LDA(1, ad)
    if (pb) {
      STAGE_B(T + 2, bs2, 0)
      STAGE_B(T + 2, bs2, 1)
    }
    __builtin_amdgcn_s_barrier();
    asm volatile("s_waitcnt lgkmcnt(0)" ::: "memory");
    __builtin_amdgcn_sched_barrier(0);
    MMA()
    // ---- tile boundary: counted drain + barrier ----
    if (pa) {
      if (pb) {
        asm volatile("s_waitcnt vmcnt(4)" ::: "memory");  // A(T+1)+B(T+1) in
      } else {
        asm volatile("s_waitcnt vmcnt(0)" ::: "memory");
      }
    }
    __builtin_amdgcn_s_barrier();
    __builtin_amdgcn_sched_barrier(0);
    bsc = (bsc == 2) ? 0 : bsc + 1;
  }

  // ---------------- epilogue ----------------
  const int row0 = m_id * 128 + wr * 64;
  const int col0 = n_id * 256 + wc * 64;

  float bv[4];
#pragma unroll
  for (int n = 0; n < 4; n++) {
    int col = col0 + n * 16 + l15;
    if (QKVMODE)
      bv[n] = col < 2048 ? b0[col] : (col < 4096 ? b1[col - 2048] : b2[col - 4096]);
    else
      bv[n] = b0[col];
  }

  if (QKVMODE && n_id >= 16) {
    // V panel -> Vt[bh][d][l], packed 8B stores
    const int bblk = row0 >> 11;
#pragma unroll
    for (int n = 0; n < 4; n++) {
      int vcol = col0 + n * 16 + l15 - 4096;
      int hh = vcol >> 7, dd = vcol & 127;
      size_t vbase = ((size_t)(bblk * 16 + hh) * 128 + dd) * (size_t)LSEQ;
#pragma unroll
      for (int mi = 0; mi < 4; mi++) {
        int rowb = row0 + mi * 16 + l4 * 4;
        unsigned short t4[4];
#pragma unroll
        for (int r = 0; r < 4; r++) t4[r] = f2bf(acc[mi][n][r] + bv[n]);
        *(uint2*)(Vt + vbase + (rowb & (LSEQ - 1))) = *(const uint2*)t4;
      }
    }
    return;
  }

  if (QKVMODE && n_id < 16) {
    // fused per-head (128-col) L2 norm over q/k, f32-exact, then bf16 store
    float* sp = (float*)&Ab[0][0];  // [8 waves][64 rows]
    __syncthreads();
#pragma unroll
    for (int mi = 0; mi < 4; mi++) {
#pragma unroll
      for (int r = 0; r < 4; r++) {
        float ss = 0.f;
#pragma unroll
        for (int n = 0; n < 4; n++) {
          float v = acc[mi][n][r] + bv[n];
          ss += v * v;
        }
        ss += __shfl_xor(ss, 1);
        ss += __shfl_xor(ss, 2);
        ss += __shfl_xor(ss, 4);
        ss += __shfl_xor(ss, 8);
        if (l15 == 0) sp[wave * 64 + mi * 16 + l4 * 4 + r] = ss;
      }
    }
    __syncthreads();
#pragma unroll
    for (int mi = 0; mi < 4; mi++) {
#pragma unroll
      for (int r = 0; r < 4; r++) {
        int idx = mi * 16 + l4 * 4 + r;
        float ss = sp[wave * 64 + idx] + sp[(wave ^ 1) * 64 + idx];
        float inv = 1.0f / (sqrtf(ss) + 1e-6f);
        int row = row0 + mi * 16 + l4 * 4 + r;
#pragma unroll
        for (int n = 0; n < 4; n++) {
          int col = col0 + n * 16 + l15;
          ((unsigned short*)Cv)[(size_t)row * N + col] = f2bf((acc[mi][n][r] + bv[n]) * inv);
        }
      }
    }
    return;
  }

  // plain store (out-proj)
#pragma unroll
  for (int n = 0; n < 4; n++) {
    int col = col0 + n * 16 + l15;
#pragma unroll
    for (int mi = 0; mi < 4; mi++) {
      int rowb = row0 + mi * 16 + l4 * 4;
#pragma unroll
      for (int r = 0; r < 4; r++) {
        float v = acc[mi][n][r] + bv[n];
        if (OUT_BF16)
          ((unsigned short*)Cv)[(size_t)(rowb + r) * N + col] = f2bf(v);
        else
          ((float*)Cv)[(size_t)(rowb + r) * N + col] = v;
      }
    }
  }
#undef STAGE_A
#undef STAGE_B
#undef LDA
#undef LDB
#undef MMA
}

// ---------------- attention v4 (round-7 core; Q pre-normalized) ----------------
__global__ __launch_bounds__(256) void attn4_k(
    const unsigned short* __restrict__ QKV, const unsigned short* __restrict__ Vt,
    unsigned short* __restrict__ Na, unsigned short* __restrict__ Nb,
    float* __restrict__ Dw) {
  __shared__ __align__(16) unsigned short Ks[2][32 * 128];  // pitch 256B, XOR (row&7)<<4
  __shared__ __align__(16) unsigned short Vs[2][128 * 40];  // pitch 80B, no XOR

  const int id = blockIdx.x;
  const int xcd = id & 7, sl = id >> 3;
  const int bh = xcd * 4 + (sl >> 5);
  const int kvh = (sl >> 4) & 1, qb = sl & 15;
  const int b = bh >> 4, h = bh & 15;
  const int q0 = qb * 128;
  const int kvbase = kvh * (LSEQ / 2);
  const int tid = threadIdx.x, wave = tid >> 6, lane = tid & 63;
  const int l15 = lane & 15, l4 = lane >> 4;
  const float scale = 0.08838834764831845f;  // 1/sqrt(128)

  bf16x8 qf[2][4];
#pragma unroll
  for (int rg = 0; rg < 2; rg++) {
    const unsigned short* qp =
        QKV + ((size_t)(b * LSEQ + q0 + wave * 32 + rg * 16 + l15)) * QKVS + h * HD + l4 * 8;
#pragma unroll
    for (int kk = 0; kk < 4; kk++) qf[rg][kk] = ld_frag(qp + kk * 32);
  }

  f32x4 oacc[2][8] = {};
  float den[2] = {0.f, 0.f};
  uint4 pk[2], pv[2];

  const unsigned short* Kb = QKV + ((size_t)(b * LSEQ)) * QKVS + 2048 + h * HD;
  const unsigned short* Vb = Vt + ((size_t)bh * HD) * LSEQ;
  const int kr0 = tid >> 4, kc = tid & 15;
  const int vr0 = tid >> 2, vc = tid & 3;
  const int srcA = ((l4 * 2) & 3) * 16 + l15;
  const int srcB = ((l4 * 2 + 1) & 3) * 16 + l15;
  const bool hiSel = (l4 >= 2);

#pragma unroll
  for (int i = 0; i < 2; i++) {
    pk[i] = *(const uint4*)(Kb + (size_t)(kvbase + kr0 + i * 16) * QKVS + kc * 8);
    pv[i] = *(const uint4*)(Vb + (size_t)(vr0 + i * 64) * LSEQ + kvbase + vc * 8);
  }
#pragma unroll
  for (int i = 0; i < 2; i++) {
    int kr = kr0 + i * 16;
    *(uint4*)((char*)&Ks[0][0] + kr * 256 + ((kc ^ (kr & 7)) << 4)) = pk[i];
    int vr = vr0 + i * 64;
    *(uint4*)((char*)&Vs[0][0] + vr * 80 + vc * 16) = pv[i];
  }

  for (int t = 0; t < 32; t++) {
    const int cur = t & 1;
    __syncthreads();
    if (t + 1 < 32) {
      const int kvn = kvbase + (t + 1) * 32;
#pragma unroll
      for (int i = 0; i < 2; i++) {
        pk[i] = *(const uint4*)(Kb + (size_t)(kvn + kr0 + i * 16) * QKVS + kc * 8);
        pv[i] = *(const uint4*)(Vb + (size_t)(vr0 + i * 64) * LSEQ + kvn + vc * 8);
      }
    }

    f32x4 sacc[2][2] = {};
    char* ksb = (char*)&Ks[cur][0];
    __builtin_amdgcn_s_setprio(1);
#pragma unroll
    for (int ni = 0; ni < 2; ni++) {
#pragma unroll
      for (int kk = 0; kk < 4; kk++) {
        bf16x8 kf = ld_frag(ksb + (ni * 16 + l15) * 256 + (((kk * 4 + l4) ^ (l15 & 7)) << 4));
        sacc[0][ni] = __builtin_amdgcn_mfma_f32_16x16x32_bf16(kf, qf[0][kk], sacc[0][ni], 0, 0, 0);
        sacc[1][ni] = __builtin_amdgcn_mfma_f32_16x16x32_bf16(kf, qf[1][kk], sacc[1][ni], 0, 0, 0);
      }
    }
    __builtin_amdgcn_s_setprio(0);

    bf16x8 pa[2];
#pragma unroll
    for (int rg = 0; rg < 2; rg++) {
      float pe[4], po[4];
#pragma unroll
      for (int r = 0; r < 4; r++) {
        pe[r] = __expf(sacc[rg][0][r] * scale);
        po[r] = __expf(sacc[rg][1][r] * scale);
      }
      den[rg] += (pe[0] + pe[1]) + (pe[2] + pe[3]) + (po[0] + po[1]) + (po[2] + po[3]);
      unsigned c0e = packbf(pe[0], pe[1]), c1e = packbf(pe[2], pe[3]);
      unsigned c0o = packbf(po[0], po[1]), c1o = packbf(po[2], po[3]);
      unsigned a0 = __shfl(c0e, srcA), a1 = __shfl(c0o, srcA);
      unsigned b0 = __shfl(c1e, srcA), b1 = __shfl(c1o, srcA);
      unsigned c0 = __shfl(c0e, srcB), c1 = __shfl(c0o, srcB);
      unsigned d0_ = __shfl(c1e, srcB), d1 = __shfl(c1o, srcB);
      uint4 paw;
      paw.x = hiSel ? a1 : a0;
      paw.y = hiSel ? b1 : b0;
      paw.z = hiSel ? c1 : c0;
      paw.w = hiSel ? d1 : d0_;
      pa[rg] = __builtin_bit_cast(bf16x8, paw);
    }

    char* vsb = (char*)&Vs[cur][0];
    __builtin_amdgcn_s_setprio(1);
#pragma unroll
    for (int d0 = 0; d0 < 8; d0++) {
      bf16x8 vf = ld_frag(vsb + (d0 * 16 + l15) * 80 + l4 * 16);
      oacc[0][d0] = __builtin_amdgcn_mfma_f32_16x16x32_bf16(pa[0], vf, oacc[0][d0], 0, 0, 0);
      oacc[1][d0] = __builtin_amdgcn_mfma_f32_16x16x32_bf16(pa[1], vf, oacc[1][d0], 0, 0, 0);
    }
    __builtin_amdgcn_s_setprio(0);

    if (t + 1 < 32) {
      char* ksn = (char*)&Ks[cur ^ 1][0];
      char* vsn = (char*)&Vs[cur ^ 1][0];
#pragma unroll
      for (int i = 0; i < 2; i++) {
        int kr = kr0 + i * 16;
        *(uint4*)(ksn + kr * 256 + ((kc ^ (kr & 7)) << 4)) = pk[i];
        int vr = vr0 + i * 64;
        *(uint4*)(vsn + vr * 80 + vc * 16) = pv[i];
      }
    }
  }

  unsigned short* Np = kvh ? Nb : Na;
#pragma unroll
  for (int rg = 0; rg < 2; rg++) {
    float sd = den[rg];
    sd += __shfl_xor(sd, 16);
    sd += __shfl_xor(sd, 32);
    if (l4 == 0) {
      int token = b * LSEQ + q0 + wave * 32 + rg * 16 + l15;
      Dw[((size_t)kvh * MTOK + token) * NH + h] = sd;
    }
  }
#pragma unroll
  for (int rg = 0; rg < 2; rg++)
#pragma unroll
    for (int d0 = 0; d0 < 8; d0++)
#pragma unroll
      for (int r = 0; r < 4; r++) {
        int token = b * LSEQ + q0 + wave * 32 + rg * 16 + l4 * 4 + r;
        Np[(size_t)token * DM + h * HD + d0 * 16 + l15] = f2bf(oacc[rg][d0][r]);
      }
}

// ---------------- combine: ao = (n0+n1)/(d0+d1) ----------------
__global__ void comb_k(const unsigned short* __restrict__ Na,
                       const unsigned short* __restrict__ Nb,
                       const float* __restrict__ Dw, unsigned short* __restrict__ Ao) {
  int i = blockIdx.x * 256 + threadIdx.x;
  int token = i >> 8, c8 = i & 255;
  int h = c8 >> 4;
  float d = Dw[(size_t)token * NH + h] + Dw[(size_t)(MTOK + token) * NH + h];
  float inv = 1.0f / d;
  uint4 w0 = ((const uint4*)Na)[i];
  uint4 w1 = ((const uint4*)Nb)[i];
  const unsigned* a = (const unsigned*)&w0;
  const unsigned* bq = (const unsigned*)&w1;
  uint4 o;
  unsigned* ow = (unsigned*)&o;
#pragma unroll
  for (int m = 0; m < 4; m++) {
    float lo = (bf2f((unsigned short)(a[m] & 0xffff)) + bf2f((unsigned short)(bq[m] & 0xffff))) * inv;
    float hi = (bf2f((unsigned short)(a[m] >> 16)) + bf2f((unsigned short)(bq[m] >> 16))) * inv;
    ow[m] = packbf(lo, hi);
  }
  ((uint4*)Ao)[i] = o;
}

extern "C" void kernel_launch(void* const* d_in, const int* in_sizes, int n_in,
                              void* d_out, int out_size, void* d_ws, size_t ws_size,
                              hipStream_t stream) {
  const float* x  = (const float*)d_in[0];
  const float* Wq = (const float*)d_in[1];
  const float* bq = (const float*)d_in[2];
  const float* Wk = (const float*)d_in[3];
  const float* bk = (const float*)d_in[4];
  const float* Wv = (const float*)d_in[5];
  const float* bv = (const float*)d_in[6];
  const float* Wo = (const float*)d_in[7];
  const float* bo = (const float*)d_in[8];

  char* ws = (char*)d_ws;
  unsigned short* xb   = (unsigned short*)(ws + 0);          // [0,16M): x bf16 -> num partial A
  unsigned short* wqkv = (unsigned short*)(ws + 16777216);   // [16M,40M): Wq|Wk|Wv bf16
  unsigned short* wob  = (unsigned short*)(ws + 41943040);   // [40M,48M): Wo bf16
  unsigned short* qkv  = (unsigned short*)(ws + 50364416);   // 48 MB region (q|k cols used)
  unsigned short* vt   = (unsigned short*)(ws + 100696064);  // 16.8 MB (transposed V)
  float*          dwp  = (float*)(ws + 16777216);            // alias wqkv (dead after QKV gemm)
  unsigned short* na   = xb;                                  // alias xb
  unsigned short* nb   = (unsigned short*)d_out;              // d_out as scratch until out-proj
  unsigned short* ao   = qkv;                                 // alias qkv base after attn

  // 1. all casts in one launch
  cvtall_k<<<12288, 256, 0, stream>>>(x, Wq, Wk, Wv, Wo, xb, wqkv, wob);

  // 2. fused QKV projection + q/k-norm + transposed V (768 blocks, 3.0 rounds)
  gemmv5_bt<1, 1><<<(MTOK / 128) * (QKVS / 256), 512, 0, stream>>>(
      xb, wqkv, bq, bk, bv, qkv, vt, MTOK, QKVS, DM);

  // 3. attention (KV-split x2)
  attn4_k<<<1024, 256, 0, stream>>>(qkv, vt, na, nb, dwp);

  // 4. combine partials -> ao (bf16)
  comb_k<<<4096, 256, 0, stream>>>(na, nb, dwp, ao);

  // 5. output projection (f32 out, 256 blocks = 1.0 round)
  gemmv5_bt<0, 0><<<(MTOK / 128) * (DM / 256), 512, 0, stream>>>(
      ao, wob, bo, bo, bo, (float*)d_out, nullptr, MTOK, DM, DM);
}

// Round 14
// 284.099 us; speedup vs baseline: 1.4166x; 1.0288x over previous
//
#include <hip/hip_runtime.h>

// QKNorm MHA: B=2, L=2048, D=2048, H=16, hd=128.
// Round 14: KV-split retired — attention (attn5) covers the full KV range per
// block (grid 512, tail-free) and writes final O = num/den directly (den moved
// to row-lanes via 8 shuffles). comb_k deleted; 4 launches total.
// GEMM (gemmv5, fine-phase counted-vmcnt) and cvtall unchanged from r13.

#define DM   2048
#define HD   128
#define NH   16
#define LSEQ 2048
#define NB   2
#define MTOK 4096  // NB*LSEQ
#define QKVS 6144  // fused row stride

typedef __bf16 bf16x8 __attribute__((ext_vector_type(8)));
typedef float  f32x4  __attribute__((ext_vector_type(4)));

__device__ __forceinline__ unsigned short f2bf(float f) {
  unsigned u = __builtin_bit_cast(unsigned, f);
  u += 0x7fffu + ((u >> 16) & 1u);
  return (unsigned short)(u >> 16);
}
__device__ __forceinline__ unsigned packbf(float lo, float hi) {
  return (unsigned)f2bf(lo) | ((unsigned)f2bf(hi) << 16);
}
__device__ __forceinline__ float bf2f(unsigned short h) {
  unsigned u = ((unsigned)h) << 16;
  return __builtin_bit_cast(float, u);
}
__device__ __forceinline__ void gload16(const unsigned short* gc, unsigned short* l) {
  unsigned short* g = const_cast<unsigned short*>(gc);
  __builtin_amdgcn_global_load_lds((__attribute__((address_space(1))) void*)g,
                                   (__attribute__((address_space(3))) void*)l, 16, 0, 0);
}
__device__ __forceinline__ bf16x8 ld_frag(const void* p) {
  return __builtin_bit_cast(bf16x8, *(const uint4*)p);
}

// ------ fused f32->bf16 cast: x, Wq, Wk, Wv, Wo in one launch ------
__global__ void cvtall_k(const float* __restrict__ x, const float* __restrict__ Wq,
                         const float* __restrict__ Wk, const float* __restrict__ Wv,
                         const float* __restrict__ Wo, unsigned short* __restrict__ xb,
                         unsigned short* __restrict__ wqkv, unsigned short* __restrict__ wob) {
  const int xc = MTOK * DM / 8;    // 1048576
  const int per = DM * DM / 8;     // 524288
  int i = blockIdx.x * blockDim.x + threadIdx.x;
  const float* s;
  unsigned short* d;
  int j;
  if (i < xc) { s = x; d = xb; j = i; }
  else if (i < xc + per) { s = Wq; d = wqkv; j = i - xc; }
  else if (i < xc + 2 * per) { s = Wk; d = wqkv + DM * DM; j = i - xc - per; }
  else if (i < xc + 3 * per) { s = Wv; d = wqkv + 2 * DM * DM; j = i - xc - 2 * per; }
  else { s = Wo; d = wob; j = i - xc - 3 * per; }
  const float4* s4 = (const float4*)s;
  float4 a = s4[2 * j], b = s4[2 * j + 1];
  uint4 o;
  o.x = packbf(a.x, a.y);
  o.y = packbf(a.z, a.w);
  o.z = packbf(b.x, b.y);
  o.w = packbf(b.z, b.w);
  ((uint4*)d)[j] = o;
}

// ========== GEMM BM=128 BN=256 BK=64, fine-phase, counted vmcnt (r13) ==========
template <int OUT_BF16, int QKVMODE>
__global__ __launch_bounds__(512) void gemmv5_bt(
    const unsigned short* __restrict__ A, const unsigned short* __restrict__ Bm,
    const float* __restrict__ b0, const float* __restrict__ b1,
    const float* __restrict__ b2, void* __restrict__ Cv,
    unsigned short* __restrict__ Vt, int M, int N, int K) {
  __shared__ unsigned short Ab[2][128 * 64];  // 16 KiB each
  __shared__ unsigned short Bb[3][256 * 64];  // 32 KiB each (128 KiB total)
  const int tid = threadIdx.x, wave = tid >> 6, lane = tid & 63;
  const int l15 = lane & 15, l4 = lane >> 4;
  const int wr = wave >> 2, wc = wave & 3;

  const int np = N >> 8;
  int n_id, m_id;
  if ((np & 7) == 0) {
    int cpx = np >> 3;
    int xcd = blockIdx.x & 7, r = blockIdx.x >> 3;
    n_id = xcd * cpx + r % cpx;
    m_id = r / cpx;
  } else {
    n_id = blockIdx.x % np;
    m_id = blockIdx.x / np;
  }
  const size_t ra0 = (size_t)m_id * 128, rb0 = (size_t)n_id * 256;
  const int NT = K >> 6;

  const int arow = tid >> 3, acg = (tid & 7) ^ (arow & 7);
  int brow[2], bcg[2];
#pragma unroll
  for (int j = 0; j < 2; j++) {
    int c = j * 512 + tid;
    brow[j] = c >> 3;
    bcg[j] = (c & 7) ^ (brow[j] & 7);
  }

#define STAGE_A(kt, slot)                                                       \
  {                                                                             \
    _Pragma("unroll") for (int h = 0; h < 2; h++) {                             \
      gload16(A + (ra0 + h * 64 + arow) * (size_t)K + ((kt) << 6) + acg * 8,    \
              &Ab[slot][(h * 512 + wave * 64) * 8]);                            \
    }                                                                           \
  }

#define STAGE_B(kt, slot, half)                                                 \
  {                                                                             \
    _Pragma("unroll") for (int j = 0; j < 2; j++) {                             \
      gload16(Bm + (rb0 + (half)*128 + brow[j]) * (size_t)K + ((kt) << 6) +     \
                  bcg[j] * 8,                                                   \
              &Bb[slot][((half)*1024 + j * 512 + wave * 64) * 8]);              \
    }                                                                           \
  }

#define LDA(kh, slot)                                                           \
  _Pragma("unroll") for (int mi = 0; mi < 4; mi++) {                            \
    int row = wr * 64 + mi * 16 + l15;                                          \
    int cl = ((kh)*4 + l4) ^ (row & 7);                                         \
    af[mi] = ld_frag((char*)&Ab[slot][0] + row * 128 + cl * 16);                \
  }

#define LDB(kh, slot)                                                           \
  _Pragma("unroll") for (int n = 0; n < 4; n++) {                               \
    int row = wc * 64 + n * 16 + l15;                                           \
    int cl = ((kh)*4 + l4) ^ (row & 7);                                         \
    bf_[n] = ld_frag((char*)&Bb[slot][0] + row * 128 + cl * 16);                \
  }

#define MMA()                                                                   \
  __builtin_amdgcn_s_setprio(1);                                                \
  _Pragma("unroll") for (int mi = 0; mi < 4; mi++)                              \
      _Pragma("unroll") for (int n = 0; n < 4; n++)                             \
          acc[mi][n] = __builtin_amdgcn_mfma_f32_16x16x32_bf16(                 \
              af[mi], bf_[n], acc[mi][n], 0, 0, 0);                             \
  __builtin_amdgcn_s_setprio(0);

  f32x4 acc[4][4] = {};
  bf16x8 af[4], bf_[4];

  STAGE_A(0, 0)
  STAGE_B(0, 0, 0)
  STAGE_B(0, 0, 1)
  STAGE_B(1, 1, 0)
  STAGE_B(1, 1, 1)
  asm volatile("s_waitcnt vmcnt(4)" ::: "memory");
  __builtin_amdgcn_s_barrier();
  __builtin_amdgcn_sched_barrier(0);

  int bsc = 0;
  for (int T = 0; T < NT; ++T) {
    const int ad = T & 1, an = ad ^ 1;
    int bs2 = bsc + 2;
    if (bs2 >= 3) bs2 -= 3;
    const bool pa = (T + 1 < NT), pb = (T + 2 < NT);

    LDB(0, bsc)
    LDA(0, ad)
    if (pa) STAGE_A(T + 1, an)
    __builtin_amdgcn_s_barrier();
    asm volatile("s_waitcnt lgkmcnt(0)" ::: "memory");
    __builtin_amdgcn_sched_barrier(0);
    MMA()
    __builtin_amdgcn_s_barrier();
    LDB(1, bsc)
    LDA(1, ad)
    if (pb) {
      STAGE_B(T + 2, bs2, 0)
      STAGE_B(T + 2, bs2, 1)
    }
    __builtin_amdgcn_s_barrier();
    asm volatile("s_waitcnt lgkmcnt(0)" ::: "memory");
    __builtin_amdgcn_sched_barrier(0);
    MMA()
    if (pa) {
      if (pb) {
        asm volatile("s_waitcnt vmcnt(4)" ::: "memory");
      } else {
        asm volatile("s_waitcnt vmcnt(0)" ::: "memory");
      }
    }
    __builtin_amdgcn_s_barrier();
    __builtin_amdgcn_sched_barrier(0);
    bsc = (bsc == 2) ? 0 : bsc + 1;
  }

  // ---------------- epilogue ----------------
  const int row0 = m_id * 128 + wr * 64;
  const int col0 = n_id * 256 + wc * 64;

  float bv[4];
#pragma unroll
  for (int n = 0; n < 4; n++) {
    int col = col0 + n * 16 + l15;
    if (QKVMODE)
      bv[n] = col < 2048 ? b0[col] : (col < 4096 ? b1[col - 2048] : b2[col - 4096]);
    else
      bv[n] = b0[col];
  }

  if (QKVMODE && n_id >= 16) {
    const int bblk = row0 >> 11;
#pragma unroll
    for (int n = 0; n < 4; n++) {
      int vcol = col0 + n * 16 + l15 - 4096;
      int hh = vcol >> 7, dd = vcol & 127;
      size_t vbase = ((size_t)(bblk * 16 + hh) * 128 + dd) * (size_t)LSEQ;
#pragma unroll
      for (int mi = 0; mi < 4; mi++) {
        int rowb = row0 + mi * 16 + l4 * 4;
        unsigned short t4[4];
#pragma unroll
        for (int r = 0; r < 4; r++) t4[r] = f2bf(acc[mi][n][r] + bv[n]);
        *(uint2*)(Vt + vbase + (rowb & (LSEQ - 1))) = *(const uint2*)t4;
      }
    }
    return;
  }

  if (QKVMODE && n_id < 16) {
    float* sp = (float*)&Ab[0][0];  // [8 waves][64 rows]
    __syncthreads();
#pragma unroll
    for (int mi = 0; mi < 4; mi++) {
#pragma unroll
      for (int r = 0; r < 4; r++) {
        float ss = 0.f;
#pragma unroll
        for (int n = 0; n < 4; n++) {
          float v = acc[mi][n][r] + bv[n];
          ss += v * v;
        }
        ss += __shfl_xor(ss, 1);
        ss += __shfl_xor(ss, 2);
        ss += __shfl_xor(ss, 4);
        ss += __shfl_xor(ss, 8);
        if (l15 == 0) sp[wave * 64 + mi * 16 + l4 * 4 + r] = ss;
      }
    }
    __syncthreads();
#pragma unroll
    for (int mi = 0; mi < 4; mi++) {
#pragma unroll
      for (int r = 0; r < 4; r++) {
        int idx = mi * 16 + l4 * 4 + r;
        float ss = sp[wave * 64 + idx] + sp[(wave ^ 1) * 64 + idx];
        float inv = 1.0f / (sqrtf(ss) + 1e-6f);
        int row = row0 + mi * 16 + l4 * 4 + r;
#pragma unroll
        for (int n = 0; n < 4; n++) {
          int col = col0 + n * 16 + l15;
          ((unsigned short*)Cv)[(size_t)row * N + col] = f2bf((acc[mi][n][r] + bv[n]) * inv);
        }
      }
    }
    return;
  }

#pragma unroll
  for (int n = 0; n < 4; n++) {
    int col = col0 + n * 16 + l15;
#pragma unroll
    for (int mi = 0; mi < 4; mi++) {
      int rowb = row0 + mi * 16 + l4 * 4;
#pragma unroll
      for (int r = 0; r < 4; r++) {
        float v = acc[mi][n][r] + bv[n];
        if (OUT_BF16)
          ((unsigned short*)Cv)[(size_t)(rowb + r) * N + col] = f2bf(v);
        else
          ((float*)Cv)[(size_t)(rowb + r) * N + col] = v;
      }
    }
  }
#undef STAGE_A
#undef STAGE_B
#undef LDA
#undef LDB
#undef MMA
}

// ---------------- attention v5: full KV range, direct O output ----------------
// grid 512: xcd=id&7 owns 4 heads; per head 16 qb. 4 waves x 32 q-rows,
// KVBLK=32 double-buffered, swapped QK^T, register P. Writes O=num/den (bf16).
__global__ __launch_bounds__(256) void attn5_k(
    const unsigned short* __restrict__ QKV, const unsigned short* __restrict__ Vt,
    unsigned short* __restrict__ Ao) {
  __shared__ __align__(16) unsigned short Ks[2][32 * 128];  // pitch 256B, XOR (row&7)<<4
  __shared__ __align__(16) unsigned short Vs[2][128 * 40];  // pitch 80B, no XOR

  const int id = blockIdx.x;
  const int xcd = id & 7, sl = id >> 3;      // sl in 0..63
  const int bh = xcd * 4 + (sl >> 4);
  const int qb = sl & 15;
  const int b = bh >> 4, h = bh & 15;
  const int q0 = qb * 128;
  const int tid = threadIdx.x, wave = tid >> 6, lane = tid & 63;
  const int l15 = lane & 15, l4 = lane >> 4;
  const float scale = 0.08838834764831845f;  // 1/sqrt(128)

  bf16x8 qf[2][4];
#pragma unroll
  for (int rg = 0; rg < 2; rg++) {
    const unsigned short* qp =
        QKV + ((size_t)(b * LSEQ + q0 + wave * 32 + rg * 16 + l15)) * QKVS + h * HD + l4 * 8;
#pragma unroll
    for (int kk = 0; kk < 4; kk++) qf[rg][kk] = ld_frag(qp + kk * 32);
  }

  f32x4 oacc[2][8] = {};
  float den[2] = {0.f, 0.f};
  uint4 pk[2], pv[2];

  const unsigned short* Kb = QKV + ((size_t)(b * LSEQ)) * QKVS + 2048 + h * HD;
  const unsigned short* Vb = Vt + ((size_t)bh * HD) * LSEQ;
  const int kr0 = tid >> 4, kc = tid & 15;
  const int vr0 = tid >> 2, vc = tid & 3;
  const int srcA = ((l4 * 2) & 3) * 16 + l15;
  const int srcB = ((l4 * 2 + 1) & 3) * 16 + l15;
  const bool hiSel = (l4 >= 2);

#pragma unroll
  for (int i = 0; i < 2; i++) {
    pk[i] = *(const uint4*)(Kb + (size_t)(kr0 + i * 16) * QKVS + kc * 8);
    pv[i] = *(const uint4*)(Vb + (size_t)(vr0 + i * 64) * LSEQ + vc * 8);
  }
#pragma unroll
  for (int i = 0; i < 2; i++) {
    int kr = kr0 + i * 16;
    *(uint4*)((char*)&Ks[0][0] + kr * 256 + ((kc ^ (kr & 7)) << 4)) = pk[i];
    int vr = vr0 + i * 64;
    *(uint4*)((char*)&Vs[0][0] + vr * 80 + vc * 16) = pv[i];
  }

  for (int t = 0; t < 64; t++) {
    const int cur = t & 1;
    __syncthreads();
    if (t + 1 < 64) {
      const int kvn = (t + 1) * 32;
#pragma unroll
      for (int i = 0; i < 2; i++) {
        pk[i] = *(const uint4*)(Kb + (size_t)(kvn + kr0 + i * 16) * QKVS + kc * 8);
        pv[i] = *(const uint4*)(Vb + (size_t)(vr0 + i * 64) * LSEQ + kvn + vc * 8);
      }
    }

    f32x4 sacc[2][2] = {};
    char* ksb = (char*)&Ks[cur][0];
    __builtin_amdgcn_s_setprio(1);
#pragma unroll
    for (int ni = 0; ni < 2; ni++) {
#pragma unroll
      for (int kk = 0; kk < 4; kk++) {
        bf16x8 kf = ld_frag(ksb + (ni * 16 + l15) * 256 + (((kk * 4 + l4) ^ (l15 & 7)) << 4));
        sacc[0][ni] = __builtin_amdgcn_mfma_f32_16x16x32_bf16(kf, qf[0][kk], sacc[0][ni], 0, 0, 0);
        sacc[1][ni] = __builtin_amdgcn_mfma_f32_16x16x32_bf16(kf, qf[1][kk], sacc[1][ni], 0, 0, 0);
      }
    }
    __builtin_amdgcn_s_setprio(0);

    bf16x8 pa[2];
#pragma unroll
    for (int rg = 0; rg < 2; rg++) {
      float pe[4], po[4];
#pragma unroll
      for (int r = 0; r < 4; r++) {
        pe[r] = __expf(sacc[rg][0][r] * scale);
        po[r] = __expf(sacc[rg][1][r] * scale);
      }
      den[rg] += (pe[0] + pe[1]) + (pe[2] + pe[3]) + (po[0] + po[1]) + (po[2] + po[3]);
      unsigned c0e = packbf(pe[0], pe[1]), c1e = packbf(pe[2], pe[3]);
      unsigned c0o = packbf(po[0], po[1]), c1o = packbf(po[2], po[3]);
      unsigned a0 = __shfl(c0e, srcA), a1 = __shfl(c0o, srcA);
      unsigned b0 = __shfl(c1e, srcA), b1 = __shfl(c1o, srcA);
      unsigned c0 = __shfl(c0e, srcB), c1 = __shfl(c0o, srcB);
      unsigned d0_ = __shfl(c1e, srcB), d1 = __shfl(c1o, srcB);
      uint4 paw;
      paw.x = hiSel ? a1 : a0;
      paw.y = hiSel ? b1 : b0;
      paw.z = hiSel ? c1 : c0;
      paw.w = hiSel ? d1 : d0_;
      pa[rg] = __builtin_bit_cast(bf16x8, paw);
    }

    char* vsb = (char*)&Vs[cur][0];
    __builtin_amdgcn_s_setprio(1);
#pragma unroll
    for (int d0 = 0; d0 < 8; d0++) {
      bf16x8 vf = ld_frag(vsb + (d0 * 16 + l15) * 80 + l4 * 16);
      oacc[0][d0] = __builtin_amdgcn_mfma_f32_16x16x32_bf16(pa[0], vf, oacc[0][d0], 0, 0, 0);
      oacc[1][d0] = __builtin_amdgcn_mfma_f32_16x16x32_bf16(pa[1], vf, oacc[1][d0], 0, 0, 0);
    }
    __builtin_amdgcn_s_setprio(0);

    if (t + 1 < 64) {
      char* ksn = (char*)&Ks[cur ^ 1][0];
      char* vsn = (char*)&Vs[cur ^ 1][0];
#pragma unroll
      for (int i = 0; i < 2; i++) {
        int kr = kr0 + i * 16;
        *(uint4*)(ksn + kr * 256 + ((kc ^ (kr & 7)) << 4)) = pk[i];
        int vr = vr0 + i * 64;
        *(uint4*)(vsn + vr * 80 + vc * 16) = pv[i];
      }
    }
  }

  // den: full sum for q-row l15 after xor-16/32; move to l4*4+r rows via shfl
  float dinv[2][4];
#pragma unroll
  for (int rg = 0; rg < 2; rg++) {
    float sd = den[rg];
    sd += __shfl_xor(sd, 16);
    sd += __shfl_xor(sd, 32);
#pragma unroll
    for (int r = 0; r < 4; r++) dinv[rg][r] = 1.0f / __shfl(sd, l4 * 4 + r);
  }
#pragma unroll
  for (int rg = 0; rg < 2; rg++)
#pragma unroll
    for (int d0 = 0; d0 < 8; d0++)
#pragma unroll
      for (int r = 0; r < 4; r++) {
        int token = b * LSEQ + q0 + wave * 32 + rg * 16 + l4 * 4 + r;
        Ao[(size_t)token * DM + h * HD + d0 * 16 + l15] =
            f2bf(oacc[rg][d0][r] * dinv[rg][r]);
      }
}

extern "C" void kernel_launch(void* const* d_in, const int* in_sizes, int n_in,
                              void* d_out, int out_size, void* d_ws, size_t ws_size,
                              hipStream_t stream) {
  const float* x  = (const float*)d_in[0];
  const float* Wq = (const float*)d_in[1];
  const float* bq = (const float*)d_in[2];
  const float* Wk = (const float*)d_in[3];
  const float* bk = (const float*)d_in[4];
  const float* Wv = (const float*)d_in[5];
  const float* bv = (const float*)d_in[6];
  const float* Wo = (const float*)d_in[7];
  const float* bo = (const float*)d_in[8];

  char* ws = (char*)d_ws;
  unsigned short* xb   = (unsigned short*)(ws + 0);          // [0,16M): x bf16 -> attn out
  unsigned short* wqkv = (unsigned short*)(ws + 16777216);   // [16M,40M): Wq|Wk|Wv bf16
  unsigned short* wob  = (unsigned short*)(ws + 41943040);   // [40M,48M): Wo bf16
  unsigned short* qkv  = (unsigned short*)(ws + 50364416);   // 48 MB region (q|k cols used)
  unsigned short* vt   = (unsigned short*)(ws + 100696064);  // 16.8 MB (transposed V)
  unsigned short* ao   = xb;                                  // x dead after QKV gemm

  // 1. all casts in one launch
  cvtall_k<<<12288, 256, 0, stream>>>(x, Wq, Wk, Wv, Wo, xb, wqkv, wob);

  // 2. fused QKV projection + q/k-norm + transposed V (768 blocks, 3.0 rounds)
  gemmv5_bt<1, 1><<<(MTOK / 128) * (QKVS / 256), 512, 0, stream>>>(
      xb, wqkv, bq, bk, bv, qkv, vt, MTOK, QKVS, DM);

  // 3. attention (full KV per block, grid 512, direct O)
  attn5_k<<<512, 256, 0, stream>>>(qkv, vt, ao);

  // 4. output projection (f32 out, 256 blocks = 1.0 round)
  gemmv5_bt<0, 0><<<(MTOK / 128) * (DM / 256), 512, 0, stream>>>(
      ao, wob, bo, bo, bo, (float*)d_out, nullptr, MTOK, DM, DM);
}